// Round 12
// baseline (438.084 us; speedup 1.0000x reference)
//
#include <hip/hip_runtime.h>
#include <stdint.h>

#define TT 64
#define NN 2048
#define EE 8192
#define DD 128
#define CAP 32

typedef __attribute__((ext_vector_type(8))) short bvec8;
typedef __attribute__((ext_vector_type(4))) float fvec4;

__device__ __forceinline__ float bf2f(uint16_t u){
  union { uint32_t i; float f; } v; v.i = ((uint32_t)u) << 16; return v.f;
}
__device__ __forceinline__ float lo16(uint32_t u){
  union { uint32_t i; float f; } v; v.i = u << 16; return v.f;
}
__device__ __forceinline__ float hi16(uint32_t u){
  union { uint32_t i; float f; } v; v.i = u & 0xffff0000u; return v.f;
}
__device__ __forceinline__ uint16_t f2bf(float f){
  union { float f; uint32_t i; } v; v.f = f;
  uint32_t r = v.i + 0x7fffu + ((v.i >> 16) & 1u);
  return (uint16_t)(r >> 16);
}
// packed f32x2 -> bf16x2 (RNE), single VALU instr
__device__ __forceinline__ uint32_t cvtpk(float lo, float hi){
  uint32_t r;
  asm("v_cvt_pk_bf16_f32 %0, %1, %2" : "=v"(r) : "v"(lo), "v"(hi));
  return r;
}
__device__ __forceinline__ fvec4 mfma16(bvec8 a, bvec8 b, fvec4 c){
  return __builtin_amdgcn_mfma_f32_16x16x32_bf16(a, b, c, 0, 0, 0);
}
// 4 payload values in k-slots (g*8+0..3), zeros in slots 4..7. Both operands
// of a product use the same padding -> zero slots contribute exactly 0.
__device__ __forceinline__ bvec8 pack8z(float a, float b, float c, float d){
  union { uint32_t u[4]; bvec8 v; } r;
  r.u[0] = cvtpk(a, b);
  r.u[1] = cvtpk(c, d);
  r.u[2] = 0u;
  r.u[3] = 0u;
  return r.v;
}

// ---------------- merged init: CSR fill + weight prep + emb gather ----------------
// esw layout: per row, CAP interleaved (key/src, weight) int pairs.
__global__ void k_init(const int* __restrict__ dst, int* __restrict__ cnt,
                       int* __restrict__ esw,
                       const float* __restrict__ Wp, const float* __restrict__ Wq,
                       const float* __restrict__ Wk, const float* __restrict__ Wv,
                       const float* __restrict__ bq, const float* __restrict__ bk,
                       const float* __restrict__ bv,
                       uint16_t* __restrict__ WpHi, uint16_t* __restrict__ WpLo,
                       uint16_t* __restrict__ QHi, float* __restrict__ biasPad,
                       const int* __restrict__ ids, const float* __restrict__ emb,
                       uint16_t* __restrict__ x){
  int bid = blockIdx.x;
  if (bid < 2048){                                    // ---- fill (T*E threads)
    int tid = bid * 256 + threadIdx.x;
    int t = tid >> 13, e = tid & (EE - 1);
    int d = dst[tid];
    int row = t * NN + d;
    int pos = atomicAdd(&cnt[row], 1);
    if (pos < CAP) esw[(size_t)row * 2 * CAP + 2 * pos] = e;
  } else if (bid < 2048 + 47){                        // ---- weight prep
    int tid = (bid - 2048) * 256 + threadIdx.x;
    if (tid < 2048){
      int lane = tid & 63, kc = (tid >> 6) & 3, ct = tid >> 8;
      int g = lane >> 4, l15 = lane & 15;
      #pragma unroll
      for (int j = 0; j < 8; ++j){
        int k = kc * 32 + g * 8 + j;
        int col = ct * 16 + l15;
        float v = Wp[k * DD + col];
        uint16_t h = f2bf(v);
        WpHi[(size_t)tid * 8 + j] = h;
        WpLo[(size_t)tid * 8 + j] = f2bf(v - bf2f(h));
      }
    } else if (tid < 2048 + 9216){
      int idx = tid - 2048;
      int lane = idx & 63, kc = (idx >> 6) & 3, t2 = idx >> 8;  // t2 = m*12+h
      int h = t2 % 12, m = t2 / 12;
      const float* W = (m == 0) ? Wq : (m == 1) ? Wk : Wv;
      int g = lane >> 4, l15 = lane & 15;
      #pragma unroll
      for (int j = 0; j < 8; ++j){
        int k = kc * 32 + g * 8 + j;
        float v = (l15 < 10) ? W[k * 120 + h * 10 + l15] : 0.f;
        QHi[(size_t)idx * 8 + j] = f2bf(v);
      }
    } else if (tid < 2048 + 9216 + 576){
      int idx = tid - (2048 + 9216);
      int m = idx / 192, rest = idx % 192;
      int h = rest / 16, d = rest % 16;
      const float* B = (m == 0) ? bq : (m == 1) ? bk : bv;
      biasPad[idx] = (d < 10) ? B[h * 10 + d] : 0.f;
    }
  } else {                                            // ---- x0 = emb[ids] (T*N*16 threads)
    int tid = (bid - 2095) * 256 + threadIdx.x;
    int row = tid >> 4, c8 = tid & 15;
    int id = ids[row];
    const float* er = emb + (size_t)id * DD + c8 * 8;
    float4 a = *(const float4*)er;
    float4 b = *(const float4*)(er + 4);
    union { uint32_t u[4]; bvec8 v; } o;
    o.u[0] = cvtpk(a.x, a.y);
    o.u[1] = cvtpk(a.z, a.w);
    o.u[2] = cvtpk(b.x, b.y);
    o.u[3] = cvtpk(b.z, b.w);
    *(bvec8*)(x + (size_t)row * DD + c8 * 8) = o.v;
  }
}

// in-place: sort edge ids (stride-2 keys, deterministic), then convert to (src, weight)
__global__ void k_sortconv(int* __restrict__ cnt, int* __restrict__ esw,
                           const int* __restrict__ srcA, const float* __restrict__ ewA){
  int row = blockIdx.x * 256 + threadIdx.x;          // T*N threads
  if (row >= TT * NN) return;
  int t = row >> 11;
  int c = cnt[row]; if (c > CAP) c = CAP;
  cnt[row] = c;
  int* p = esw + (size_t)row * 2 * CAP;
  for (int i = 0; i < c; ++i){                        // selection sort ascending
    int mi = i, mv = p[2 * i];
    for (int j = i + 1; j < c; ++j){ int vj = p[2 * j]; if (vj < mv){ mv = vj; mi = j; } }
    if (mi != i){ p[2 * mi] = p[2 * i]; p[2 * i] = mv; }
  }
  const int* srcT = srcA + (size_t)t * EE;
  const float* ewT = ewA + (size_t)t * EE;
  for (int i = 0; i < c; ++i){
    int e = p[2 * i];
    p[2 * i]     = srcT[e];
    p[2 * i + 1] = __float_as_int(ewT[e]);
  }
}

// ---------------- fused propagate: n_hat = x + scatter; out = n_hat@Wp + bp ----------------
// 64-row blocks (grid 2048): amortize the 64KB W read over 64 rows (L2
// traffic 128MB/launch vs 512MB at 16-row blocks). Phase 1 uses r8's
// 4-row-group issue/consume pipeline (32 gather loads in flight) — safe
// here because (256,4) caps VGPR at 128 > the ~110 this needs (r8 spilled
// only because (256,6) capped at 85). CSR heads staged in LDS.
__global__ __launch_bounds__(256, 4) void k_prop(const uint16_t* __restrict__ xin,
    uint16_t* __restrict__ xout, const int* __restrict__ cnt, const int* __restrict__ esw,
    const uint16_t* __restrict__ WHi, const uint16_t* __restrict__ WLo,
    const float* __restrict__ bp, int topt){
  __shared__ uint16_t lds[64 * 136];
  __shared__ int4 eplds[256];                         // 64 rows x first 8 (src,w) pairs
  int vb = blockIdx.x;
  int b = ((vb & 7) << 8) | (vb >> 3);                // XCD swizzle: one t handled on one XCD
  int t = b >> 5, n0 = (b & 31) << 6;
  int tid = threadIdx.x, w = tid >> 6, lane = tid & 63, g = lane >> 4, l15 = lane & 15;
  const uint16_t* xt = xin + (size_t)t * NN * DD;
  int baseRow = t * NN + n0;
  // stage CSR heads: thread tid -> int4 #(tid&3) of block-row (tid>>2)
  eplds[tid] = ((const int4*)(esw + (size_t)(baseRow + (tid >> 2)) * 2 * CAP))[tid & 3];
  int myc = (lane < 16) ? cnt[baseRow + w * 16 + lane] : 0;
  __syncthreads();
  // phase 1: groups of 4 rows; issue 4x(8+1) loads, then consume
  for (int gi = 0; gi < 4; ++gi){
    int rb = w * 16 + gi * 4;                         // block-local row of group start
    uint32_t u4[4], xs[4][8];
    float wfv[4][8];
    #pragma unroll
    for (int i = 0; i < 4; ++i)
      u4[i] = *(const uint32_t*)(xt + (size_t)(n0 + rb + i) * DD + (lane << 1));
    #pragma unroll
    for (int i = 0; i < 4; ++i){
      int c = __shfl(myc, gi * 4 + i);                // wave-uniform
      const int4* epr = &eplds[(rb + i) * 4];         // LDS broadcast reads
      int4 q0 = epr[0], q1 = epr[1], q2 = epr[2], q3 = epr[3];
      int sj[8]   = {q0.x, q0.z, q1.x, q1.z, q2.x, q2.z, q3.x, q3.z};
      float wj[8] = {__int_as_float(q0.y), __int_as_float(q0.w),
                     __int_as_float(q1.y), __int_as_float(q1.w),
                     __int_as_float(q2.y), __int_as_float(q2.w),
                     __int_as_float(q3.y), __int_as_float(q3.w)};
      #pragma unroll
      for (int j = 0; j < 8; ++j){
        int s = (j < c) ? sj[j] : 0;                  // clamp garbage idx, zero weight
        wfv[i][j] = (j < c) ? wj[j] : 0.f;
        xs[i][j] = *(const uint32_t*)(xt + (size_t)s * DD + (lane << 1));
      }
    }
    #pragma unroll
    for (int i = 0; i < 4; ++i){
      float a0 = lo16(u4[i]);
      float a1 = hi16(u4[i]);
      #pragma unroll
      for (int j = 0; j < 8; ++j){
        a0 = fmaf(wfv[i][j], lo16(xs[i][j]), a0);
        a1 = fmaf(wfv[i][j], hi16(xs[i][j]), a1);
      }
      int c = __shfl(myc, gi * 4 + i);
      if (c > 8){                                     // rare tail (P ~ 2%)
        int rowg = baseRow + rb + i;
        for (int j = 8; j < c; ++j){
          int s = esw[(size_t)rowg * 2 * CAP + 2 * j];
          float wt = __int_as_float(esw[(size_t)rowg * 2 * CAP + 2 * j + 1]);
          uint32_t us = *(const uint32_t*)(xt + (size_t)s * DD + (lane << 1));
          a0 = fmaf(wt, lo16(us), a0);
          a1 = fmaf(wt, hi16(us), a1);
        }
      }
      *(uint32_t*)&lds[(rb + i) * 136 + (lane << 1)] = cvtpk(a0, a1);
    }
  }
  __syncthreads();
  // phase 2: GEMM [64x128] @ [128x128], wave w -> row-tile w (r9-proven)
  bvec8 afr[4];
  int arow = w * 16 + l15;
  #pragma unroll
  for (int kc = 0; kc < 4; ++kc)
    afr[kc] = *(const bvec8*)&lds[arow * 136 + kc * 32 + g * 8];
  fvec4 acc[8];
  #pragma unroll
  for (int i = 0; i < 8; ++i) acc[i] = fvec4{0.f, 0.f, 0.f, 0.f};
  #pragma unroll
  for (int kc = 0; kc < 4; ++kc){
    #pragma unroll
    for (int ct = 0; ct < 8; ++ct){
      size_t base = ((size_t)(ct * 4 + kc) * 64 + lane) * 8;
      acc[ct] = mfma16(afr[kc], *(const bvec8*)&WHi[base], acc[ct]);
      acc[ct] = mfma16(afr[kc], *(const bvec8*)&WLo[base], acc[ct]);
    }
  }
  __syncthreads();
  // epilogue: C + bias -> bf16 back into LDS
  #pragma unroll
  for (int ct = 0; ct < 8; ++ct){
    int col = ct * 16 + l15;
    float bias = bp[col];
    uint32_t c01 = cvtpk(acc[ct][0] + bias, acc[ct][1] + bias);
    uint32_t c23 = cvtpk(acc[ct][2] + bias, acc[ct][3] + bias);
    int r = w * 16 + g * 4;
    lds[(r + 0) * 136 + col] = (uint16_t)c01;
    lds[(r + 1) * 136 + col] = (uint16_t)(c01 >> 16);
    lds[(r + 2) * 136 + col] = (uint16_t)c23;
    lds[(r + 3) * 136 + col] = (uint16_t)(c23 >> 16);
  }
  __syncthreads();
  // store (topt: last round writes [n][t][d] for attention)
  #pragma unroll
  for (int p4 = 0; p4 < 4; ++p4){
    int chunk = p4 * 256 + tid, r = chunk >> 4, c8 = chunk & 15;
    bvec8 v = *(const bvec8*)&lds[r * 136 + c8 * 8];
    size_t dstoff;
    if (topt == 0) dstoff = ((size_t)t * NN + n0 + r) * DD + c8 * 8;
    else           dstoff = (((size_t)(n0 + r)) * TT + t) * DD + c8 * 8;
    *(bvec8*)(xout + dstoff) = v;
  }
}

// ---------------- fused QKV + attention + partial mean ----------------
// Head-per-wave; register-resident attention (zero-padded K=32 trick, r7-verified).
// Softmax scale folded into the Q pack (S' = CSC*S).
// NOTE: (256,3) is load-bearing — (256,4) squeezed VGPR 84->64 and spilled (r10).
__global__ __launch_bounds__(256, 3) void k_attn(const uint16_t* __restrict__ x3,
    const uint16_t* __restrict__ QHi, const float* __restrict__ biasPad,
    float* __restrict__ partials){
  __shared__ uint16_t seq[64 * 136];                  // 17408 B
  int n = blockIdx.x;
  int tid = threadIdx.x, w = tid >> 6, lane = tid & 63, g = lane >> 4, l15 = lane & 15;
  const uint16_t* xr = x3 + (size_t)n * TT * DD;
  #pragma unroll
  for (int p4 = 0; p4 < 4; ++p4){
    int chunk = p4 * 256 + tid, r = chunk >> 4, c8 = chunk & 15;
    *(bvec8*)&seq[r * 136 + c8 * 8] = *(const bvec8*)&xr[r * 128 + c8 * 8];
  }
  __syncthreads();                                    // the only barrier

  const float CSC = 0.31622776601683794f * 1.4426950408889634f;  // (1/sqrt(10))*log2(e)

  for (int pass = 0; pass < 3; ++pass){
    int h = pass * 4 + w;
    bvec8 qf8[4], kf8[4], vf8[4];
    #pragma unroll
    for (int m = 0; m < 3; ++m){
      fvec4 acc[4];
      #pragma unroll
      for (int i = 0; i < 4; ++i) acc[i] = fvec4{0.f, 0.f, 0.f, 0.f};
      #pragma unroll
      for (int kc = 0; kc < 4; ++kc){
        bvec8 B = *(const bvec8*)&QHi[((size_t)((m * 12 + h) * 4 + kc) * 64 + lane) * 8];
        #pragma unroll
        for (int tb = 0; tb < 4; ++tb){
          bvec8 a = *(const bvec8*)&seq[(tb * 16 + l15) * 136 + kc * 32 + g * 8];
          if (m == 2) acc[tb] = mfma16(a, B, acc[tb]);  // V: lane=d, regs=s
          else        acc[tb] = mfma16(B, a, acc[tb]);  // Q,K: lane=t, regs=d
        }
      }
      if (m == 0){                                     // Q: fold softmax scale
        float4 b4 = *(const float4*)&biasPad[(0 * 12 + h) * 16 + g * 4];
        #pragma unroll
        for (int tb = 0; tb < 4; ++tb)
          qf8[tb] = pack8z((acc[tb][0] + b4.x) * CSC, (acc[tb][1] + b4.y) * CSC,
                           (acc[tb][2] + b4.z) * CSC, (acc[tb][3] + b4.w) * CSC);
      } else if (m == 1){
        float4 b4 = *(const float4*)&biasPad[(1 * 12 + h) * 16 + g * 4];
        #pragma unroll
        for (int tb = 0; tb < 4; ++tb)
          kf8[tb] = pack8z(acc[tb][0] + b4.x, acc[tb][1] + b4.y,
                           acc[tb][2] + b4.z, acc[tb][3] + b4.w);
      } else {
        float bias = biasPad[(2 * 12 + h) * 16 + l15];  // per-d bias (lane=d)
        #pragma unroll
        for (int tb = 0; tb < 4; ++tb)
          vf8[tb] = pack8z(acc[tb][0] + bias, acc[tb][1] + bias,
                           acc[tb][2] + bias, acc[tb][3] + bias);
      }
    }
    // ---- attention, all in registers ----
    float csum = 0.f;
    #pragma unroll
    for (int tb = 0; tb < 4; ++tb){
      fvec4 p[4];
      #pragma unroll
      for (int sb = 0; sb < 4; ++sb)
        p[sb] = mfma16(kf8[sb], qf8[tb], fvec4{0.f, 0.f, 0.f, 0.f});
      // exp without rowmax: scores O(0.1); softmax shift-invariant -> exact
      float s = 0.f;
      #pragma unroll
      for (int sb = 0; sb < 4; ++sb)
        #pragma unroll
        for (int rg = 0; rg < 4; ++rg){
          float pv = exp2f(p[sb][rg]);
          p[sb][rg] = pv;
          s += pv;
        }
      s += __shfl_xor(s, 16);
      s += __shfl_xor(s, 32);
      float rinv = __builtin_amdgcn_rcpf(s);
      fvec4 o = fvec4{0.f, 0.f, 0.f, 0.f};
      #pragma unroll
      for (int sb = 0; sb < 4; ++sb){
        bvec8 pf = pack8z(p[sb][0] * rinv, p[sb][1] * rinv,
                          p[sb][2] * rinv, p[sb][3] * rinv);
        o = mfma16(pf, vf8[sb], o);
      }
      csum += o[0] + o[1] + o[2] + o[3];
    }
    csum += __shfl_xor(csum, 16);
    csum += __shfl_xor(csum, 32);
    if (g == 0 && l15 < 10)
      partials[(size_t)n * 120 + h * 10 + l15] = csum;
  }
}

// ---------------- deterministic reductions ----------------
__global__ void k_reduce(const float* __restrict__ partials, float* __restrict__ agg){
  __shared__ float red[256];
  int c = blockIdx.x, tid = threadIdx.x;
  float s = 0.f;
  for (int b = tid; b < NN; b += 256) s += partials[(size_t)b * 120 + c];
  red[tid] = s;
  __syncthreads();
  for (int st = 128; st > 0; st >>= 1){
    if (tid < st) red[tid] += red[tid + st];
    __syncthreads();
  }
  if (tid == 0) agg[c] = red[0] * (1.0f / (float)(NN * TT));
}

__global__ void k_final(const float* __restrict__ agg, const float* __restrict__ Wo,
                        const float* __restrict__ bo, float* __restrict__ out){
  __shared__ float r0[128], r1[128];
  int j = threadIdx.x;
  float a = (j < 120) ? agg[j] : 0.f;
  r0[j] = (j < 120) ? a * Wo[2 * j] : 0.f;
  r1[j] = (j < 120) ? a * Wo[2 * j + 1] : 0.f;
  __syncthreads();
  for (int st = 64; st > 0; st >>= 1){
    if (j < st){ r0[j] += r0[j + st]; r1[j] += r1[j + st]; }
    __syncthreads();
  }
  if (j == 0){ out[0] = r0[0] + bo[0]; out[1] = r1[0] + bo[1]; }
}

extern "C" void kernel_launch(void* const* d_in, const int* in_sizes, int n_in,
                              void* d_out, int out_size, void* d_ws, size_t ws_size,
                              hipStream_t stream){
  const int*   node_ids = (const int*)d_in[0];
  const int*   srcA     = (const int*)d_in[1];
  const int*   dstA     = (const int*)d_in[2];
  const float* ew       = (const float*)d_in[3];
  const float* emb      = (const float*)d_in[4];
  const float* Wp       = (const float*)d_in[5];
  const float* bp       = (const float*)d_in[6];
  const float* Wq       = (const float*)d_in[7];
  const float* bq       = (const float*)d_in[8];
  const float* Wk       = (const float*)d_in[9];
  const float* bk       = (const float*)d_in[10];
  const float* Wv       = (const float*)d_in[11];
  const float* bv       = (const float*)d_in[12];
  const float* Wo       = (const float*)d_in[13];
  const float* bo       = (const float*)d_in[14];

  char* p = (char*)d_ws;
  auto alloc = [&](size_t bytes) -> char* {
    char* r = p; p += (bytes + 255) & ~(size_t)255; return r;
  };
  // Total ~102.4 MB (proven footprint)
  uint16_t* xA    = (uint16_t*)alloc((size_t)TT * NN * DD * 2);
  uint16_t* xB    = (uint16_t*)alloc((size_t)TT * NN * DD * 2);
  int*      cnt   = (int*)alloc((size_t)TT * NN * 4);
  int*      esw   = (int*)alloc((size_t)TT * NN * 2 * CAP * 4);
  uint16_t* WpHi  = (uint16_t*)alloc(2048 * 8 * 2);
  uint16_t* WpLo  = (uint16_t*)alloc(2048 * 8 * 2);
  uint16_t* QHi   = (uint16_t*)alloc(9216 * 8 * 2);
  float*    biasP = (float*)alloc(576 * 4);
  float*    parts = (float*)alloc((size_t)NN * 120 * 4);
  float*    agg   = (float*)alloc(120 * 4);

  hipMemsetAsync(cnt, 0, (size_t)TT * NN * 4, stream);
  k_init<<<2048 + 47 + 8192, 256, 0, stream>>>(dstA, cnt, esw,
      Wp, Wq, Wk, Wv, bq, bk, bv, WpHi, WpLo, QHi, biasP,
      node_ids, emb, xA);
  k_sortconv<<<TT * NN / 256, 256, 0, stream>>>(cnt, esw, srcA, ew);
  k_prop<<<2048, 256, 0, stream>>>(xA, xB, cnt, esw, WpHi, WpLo, bp, 0);
  k_prop<<<2048, 256, 0, stream>>>(xB, xA, cnt, esw, WpHi, WpLo, bp, 0);
  k_prop<<<2048, 256, 0, stream>>>(xA, xB, cnt, esw, WpHi, WpLo, bp, 1);
  k_attn<<<NN, 256, 0, stream>>>(xB, QHi, biasP, parts);
  k_reduce<<<120, 256, 0, stream>>>(parts, agg);
  k_final<<<1, 128, 0, stream>>>(agg, Wo, bo, (float*)d_out);
}

// Round 13
// 263.543 us; speedup vs baseline: 1.6623x; 1.6623x over previous
//
#include <hip/hip_runtime.h>
#include <stdint.h>

#define TT 64
#define NN 2048
#define EE 8192
#define DD 128
#define CAP 32

typedef __attribute__((ext_vector_type(8))) short bvec8;
typedef __attribute__((ext_vector_type(4))) float fvec4;

__device__ __forceinline__ float bf2f(uint16_t u){
  union { uint32_t i; float f; } v; v.i = ((uint32_t)u) << 16; return v.f;
}
__device__ __forceinline__ float lo16(uint32_t u){
  union { uint32_t i; float f; } v; v.i = u << 16; return v.f;
}
__device__ __forceinline__ float hi16(uint32_t u){
  union { uint32_t i; float f; } v; v.i = u & 0xffff0000u; return v.f;
}
__device__ __forceinline__ uint16_t f2bf(float f){
  union { float f; uint32_t i; } v; v.f = f;
  uint32_t r = v.i + 0x7fffu + ((v.i >> 16) & 1u);
  return (uint16_t)(r >> 16);
}
// packed f32x2 -> bf16x2 (RNE), single VALU instr
__device__ __forceinline__ uint32_t cvtpk(float lo, float hi){
  uint32_t r;
  asm("v_cvt_pk_bf16_f32 %0, %1, %2" : "=v"(r) : "v"(lo), "v"(hi));
  return r;
}
__device__ __forceinline__ fvec4 mfma16(bvec8 a, bvec8 b, fvec4 c){
  return __builtin_amdgcn_mfma_f32_16x16x32_bf16(a, b, c, 0, 0, 0);
}
// 4 payload values in k-slots (g*8+0..3), zeros in slots 4..7. Both operands
// of a product use the same padding -> zero slots contribute exactly 0.
__device__ __forceinline__ bvec8 pack8z(float a, float b, float c, float d){
  union { uint32_t u[4]; bvec8 v; } r;
  r.u[0] = cvtpk(a, b);
  r.u[1] = cvtpk(c, d);
  r.u[2] = 0u;
  r.u[3] = 0u;
  return r.v;
}

// ---------------- merged init: CSR fill + weight prep + emb gather ----------------
// esw layout: per row, CAP interleaved (key/src, weight) int pairs.
__global__ void k_init(const int* __restrict__ dst, int* __restrict__ cnt,
                       int* __restrict__ esw,
                       const float* __restrict__ Wp, const float* __restrict__ Wq,
                       const float* __restrict__ Wk, const float* __restrict__ Wv,
                       const float* __restrict__ bq, const float* __restrict__ bk,
                       const float* __restrict__ bv,
                       uint16_t* __restrict__ WpHi, uint16_t* __restrict__ WpLo,
                       uint16_t* __restrict__ QHi, float* __restrict__ biasPad,
                       const int* __restrict__ ids, const float* __restrict__ emb,
                       uint16_t* __restrict__ x){
  int bid = blockIdx.x;
  if (bid < 2048){                                    // ---- fill (T*E threads)
    int tid = bid * 256 + threadIdx.x;
    int t = tid >> 13, e = tid & (EE - 1);
    int d = dst[tid];
    int row = t * NN + d;
    int pos = atomicAdd(&cnt[row], 1);
    if (pos < CAP) esw[(size_t)row * 2 * CAP + 2 * pos] = e;
  } else if (bid < 2048 + 47){                        // ---- weight prep
    int tid = (bid - 2048) * 256 + threadIdx.x;
    if (tid < 2048){
      int lane = tid & 63, kc = (tid >> 6) & 3, ct = tid >> 8;
      int g = lane >> 4, l15 = lane & 15;
      #pragma unroll
      for (int j = 0; j < 8; ++j){
        int k = kc * 32 + g * 8 + j;
        int col = ct * 16 + l15;
        float v = Wp[k * DD + col];
        uint16_t h = f2bf(v);
        WpHi[(size_t)tid * 8 + j] = h;
        WpLo[(size_t)tid * 8 + j] = f2bf(v - bf2f(h));
      }
    } else if (tid < 2048 + 9216){
      int idx = tid - 2048;
      int lane = idx & 63, kc = (idx >> 6) & 3, t2 = idx >> 8;  // t2 = m*12+h
      int h = t2 % 12, m = t2 / 12;
      const float* W = (m == 0) ? Wq : (m == 1) ? Wk : Wv;
      int g = lane >> 4, l15 = lane & 15;
      #pragma unroll
      for (int j = 0; j < 8; ++j){
        int k = kc * 32 + g * 8 + j;
        float v = (l15 < 10) ? W[k * 120 + h * 10 + l15] : 0.f;
        QHi[(size_t)idx * 8 + j] = f2bf(v);
      }
    } else if (tid < 2048 + 9216 + 576){
      int idx = tid - (2048 + 9216);
      int m = idx / 192, rest = idx % 192;
      int h = rest / 16, d = rest % 16;
      const float* B = (m == 0) ? bq : (m == 1) ? bk : bv;
      biasPad[idx] = (d < 10) ? B[h * 10 + d] : 0.f;
    }
  } else {                                            // ---- x0 = emb[ids] (T*N*16 threads)
    int tid = (bid - 2095) * 256 + threadIdx.x;
    int row = tid >> 4, c8 = tid & 15;
    int id = ids[row];
    const float* er = emb + (size_t)id * DD + c8 * 8;
    float4 a = *(const float4*)er;
    float4 b = *(const float4*)(er + 4);
    union { uint32_t u[4]; bvec8 v; } o;
    o.u[0] = cvtpk(a.x, a.y);
    o.u[1] = cvtpk(a.z, a.w);
    o.u[2] = cvtpk(b.x, b.y);
    o.u[3] = cvtpk(b.z, b.w);
    *(bvec8*)(x + (size_t)row * DD + c8 * 8) = o.v;
  }
}

// in-place: sort edge ids (stride-2 keys, deterministic), then convert to (src, weight)
__global__ void k_sortconv(int* __restrict__ cnt, int* __restrict__ esw,
                           const int* __restrict__ srcA, const float* __restrict__ ewA){
  int row = blockIdx.x * 256 + threadIdx.x;          // T*N threads
  if (row >= TT * NN) return;
  int t = row >> 11;
  int c = cnt[row]; if (c > CAP) c = CAP;
  cnt[row] = c;
  int* p = esw + (size_t)row * 2 * CAP;
  for (int i = 0; i < c; ++i){                        // selection sort ascending
    int mi = i, mv = p[2 * i];
    for (int j = i + 1; j < c; ++j){ int vj = p[2 * j]; if (vj < mv){ mv = vj; mi = j; } }
    if (mi != i){ p[2 * mi] = p[2 * i]; p[2 * i] = mv; }
  }
  const int* srcT = srcA + (size_t)t * EE;
  const float* ewT = ewA + (size_t)t * EE;
  for (int i = 0; i < c; ++i){
    int e = p[2 * i];
    p[2 * i]     = srcT[e];
    p[2 * i + 1] = __float_as_int(ewT[e]);
  }
}

// ---------------- fused propagate: n_hat = x + scatter; out = n_hat@Wp + bp ----------------
// 64-row blocks, 4-row-group issue/consume gather (32+ loads in flight/wave).
// LAUNCH-BOUNDS RULE (empirical, r3/r4/r9/r10/r12): VGPR cap ~= 256/arg for
// 256-thread blocks. This kernel needs ~110 live VGPRs -> arg=2 (cap 128).
// arg=4 capped at 64 and spilled (r8/r12: WRITE_SIZE 255MB of scratch).
__global__ __launch_bounds__(256, 2) void k_prop(const uint16_t* __restrict__ xin,
    uint16_t* __restrict__ xout, const int* __restrict__ cnt, const int* __restrict__ esw,
    const uint16_t* __restrict__ WHi, const uint16_t* __restrict__ WLo,
    const float* __restrict__ bp, int topt){
  __shared__ uint16_t lds[64 * 136];
  __shared__ int4 eplds[256];                         // 64 rows x first 8 (src,w) pairs
  int vb = blockIdx.x;
  int b = ((vb & 7) << 8) | (vb >> 3);                // XCD swizzle: one t handled on one XCD
  int t = b >> 5, n0 = (b & 31) << 6;
  int tid = threadIdx.x, w = tid >> 6, lane = tid & 63, g = lane >> 4, l15 = lane & 15;
  const uint16_t* xt = xin + (size_t)t * NN * DD;
  int baseRow = t * NN + n0;
  // stage CSR heads: thread tid -> int4 #(tid&3) of block-row (tid>>2)
  eplds[tid] = ((const int4*)(esw + (size_t)(baseRow + (tid >> 2)) * 2 * CAP))[tid & 3];
  int myc = (lane < 16) ? cnt[baseRow + w * 16 + lane] : 0;
  __syncthreads();
  // phase 1: groups of 4 rows; issue 4x(8+1) loads, then consume
  for (int gi = 0; gi < 4; ++gi){
    int rb = w * 16 + gi * 4;                         // block-local row of group start
    uint32_t u4[4], xs[4][8];
    float wfv[4][8];
    #pragma unroll
    for (int i = 0; i < 4; ++i)
      u4[i] = *(const uint32_t*)(xt + (size_t)(n0 + rb + i) * DD + (lane << 1));
    #pragma unroll
    for (int i = 0; i < 4; ++i){
      int c = __shfl(myc, gi * 4 + i);                // wave-uniform
      const int4* epr = &eplds[(rb + i) * 4];         // LDS broadcast reads
      int4 q0 = epr[0], q1 = epr[1], q2 = epr[2], q3 = epr[3];
      int sj[8]   = {q0.x, q0.z, q1.x, q1.z, q2.x, q2.z, q3.x, q3.z};
      float wj[8] = {__int_as_float(q0.y), __int_as_float(q0.w),
                     __int_as_float(q1.y), __int_as_float(q1.w),
                     __int_as_float(q2.y), __int_as_float(q2.w),
                     __int_as_float(q3.y), __int_as_float(q3.w)};
      #pragma unroll
      for (int j = 0; j < 8; ++j){
        int s = (j < c) ? sj[j] : 0;                  // clamp garbage idx, zero weight
        wfv[i][j] = (j < c) ? wj[j] : 0.f;
        xs[i][j] = *(const uint32_t*)(xt + (size_t)s * DD + (lane << 1));
      }
    }
    #pragma unroll
    for (int i = 0; i < 4; ++i){
      float a0 = lo16(u4[i]);
      float a1 = hi16(u4[i]);
      #pragma unroll
      for (int j = 0; j < 8; ++j){
        a0 = fmaf(wfv[i][j], lo16(xs[i][j]), a0);
        a1 = fmaf(wfv[i][j], hi16(xs[i][j]), a1);
      }
      int c = __shfl(myc, gi * 4 + i);
      if (c > 8){                                     // rare tail (P ~ 2%)
        int rowg = baseRow + rb + i;
        for (int j = 8; j < c; ++j){
          int s = esw[(size_t)rowg * 2 * CAP + 2 * j];
          float wt = __int_as_float(esw[(size_t)rowg * 2 * CAP + 2 * j + 1]);
          uint32_t us = *(const uint32_t*)(xt + (size_t)s * DD + (lane << 1));
          a0 = fmaf(wt, lo16(us), a0);
          a1 = fmaf(wt, hi16(us), a1);
        }
      }
      *(uint32_t*)&lds[(rb + i) * 136 + (lane << 1)] = cvtpk(a0, a1);
    }
  }
  __syncthreads();
  // phase 2: GEMM [64x128] @ [128x128], wave w -> row-tile w (r9-proven)
  bvec8 afr[4];
  int arow = w * 16 + l15;
  #pragma unroll
  for (int kc = 0; kc < 4; ++kc)
    afr[kc] = *(const bvec8*)&lds[arow * 136 + kc * 32 + g * 8];
  fvec4 acc[8];
  #pragma unroll
  for (int i = 0; i < 8; ++i) acc[i] = fvec4{0.f, 0.f, 0.f, 0.f};
  #pragma unroll
  for (int kc = 0; kc < 4; ++kc){
    #pragma unroll
    for (int ct = 0; ct < 8; ++ct){
      size_t base = ((size_t)(ct * 4 + kc) * 64 + lane) * 8;
      acc[ct] = mfma16(afr[kc], *(const bvec8*)&WHi[base], acc[ct]);
      acc[ct] = mfma16(afr[kc], *(const bvec8*)&WLo[base], acc[ct]);
    }
  }
  __syncthreads();
  // epilogue: C + bias -> bf16 back into LDS
  #pragma unroll
  for (int ct = 0; ct < 8; ++ct){
    int col = ct * 16 + l15;
    float bias = bp[col];
    uint32_t c01 = cvtpk(acc[ct][0] + bias, acc[ct][1] + bias);
    uint32_t c23 = cvtpk(acc[ct][2] + bias, acc[ct][3] + bias);
    int r = w * 16 + g * 4;
    lds[(r + 0) * 136 + col] = (uint16_t)c01;
    lds[(r + 1) * 136 + col] = (uint16_t)(c01 >> 16);
    lds[(r + 2) * 136 + col] = (uint16_t)c23;
    lds[(r + 3) * 136 + col] = (uint16_t)(c23 >> 16);
  }
  __syncthreads();
  // store (topt: last round writes [n][t][d] for attention)
  #pragma unroll
  for (int p4 = 0; p4 < 4; ++p4){
    int chunk = p4 * 256 + tid, r = chunk >> 4, c8 = chunk & 15;
    bvec8 v = *(const bvec8*)&lds[r * 136 + c8 * 8];
    size_t dstoff;
    if (topt == 0) dstoff = ((size_t)t * NN + n0 + r) * DD + c8 * 8;
    else           dstoff = (((size_t)(n0 + r)) * TT + t) * DD + c8 * 8;
    *(bvec8*)(xout + dstoff) = v;
  }
}

// ---------------- fused QKV + attention + partial mean ----------------
// Head-per-wave; register-resident attention (zero-padded K=32 trick, r7-verified).
// Softmax scale folded into the Q pack (S' = CSC*S).
// NOTE: (256,3) is load-bearing — (256,4) squeezed VGPR 84->64 and spilled (r10).
__global__ __launch_bounds__(256, 3) void k_attn(const uint16_t* __restrict__ x3,
    const uint16_t* __restrict__ QHi, const float* __restrict__ biasPad,
    float* __restrict__ partials){
  __shared__ uint16_t seq[64 * 136];                  // 17408 B
  int n = blockIdx.x;
  int tid = threadIdx.x, w = tid >> 6, lane = tid & 63, g = lane >> 4, l15 = lane & 15;
  const uint16_t* xr = x3 + (size_t)n * TT * DD;
  #pragma unroll
  for (int p4 = 0; p4 < 4; ++p4){
    int chunk = p4 * 256 + tid, r = chunk >> 4, c8 = chunk & 15;
    *(bvec8*)&seq[r * 136 + c8 * 8] = *(const bvec8*)&xr[r * 128 + c8 * 8];
  }
  __syncthreads();                                    // the only barrier

  const float CSC = 0.31622776601683794f * 1.4426950408889634f;  // (1/sqrt(10))*log2(e)

  for (int pass = 0; pass < 3; ++pass){
    int h = pass * 4 + w;
    bvec8 qf8[4], kf8[4], vf8[4];
    #pragma unroll
    for (int m = 0; m < 3; ++m){
      fvec4 acc[4];
      #pragma unroll
      for (int i = 0; i < 4; ++i) acc[i] = fvec4{0.f, 0.f, 0.f, 0.f};
      #pragma unroll
      for (int kc = 0; kc < 4; ++kc){
        bvec8 B = *(const bvec8*)&QHi[((size_t)((m * 12 + h) * 4 + kc) * 64 + lane) * 8];
        #pragma unroll
        for (int tb = 0; tb < 4; ++tb){
          bvec8 a = *(const bvec8*)&seq[(tb * 16 + l15) * 136 + kc * 32 + g * 8];
          if (m == 2) acc[tb] = mfma16(a, B, acc[tb]);  // V: lane=d, regs=s
          else        acc[tb] = mfma16(B, a, acc[tb]);  // Q,K: lane=t, regs=d
        }
      }
      if (m == 0){                                     // Q: fold softmax scale
        float4 b4 = *(const float4*)&biasPad[(0 * 12 + h) * 16 + g * 4];
        #pragma unroll
        for (int tb = 0; tb < 4; ++tb)
          qf8[tb] = pack8z((acc[tb][0] + b4.x) * CSC, (acc[tb][1] + b4.y) * CSC,
                           (acc[tb][2] + b4.z) * CSC, (acc[tb][3] + b4.w) * CSC);
      } else if (m == 1){
        float4 b4 = *(const float4*)&biasPad[(1 * 12 + h) * 16 + g * 4];
        #pragma unroll
        for (int tb = 0; tb < 4; ++tb)
          kf8[tb] = pack8z(acc[tb][0] + b4.x, acc[tb][1] + b4.y,
                           acc[tb][2] + b4.z, acc[tb][3] + b4.w);
      } else {
        float bias = biasPad[(2 * 12 + h) * 16 + l15];  // per-d bias (lane=d)
        #pragma unroll
        for (int tb = 0; tb < 4; ++tb)
          vf8[tb] = pack8z(acc[tb][0] + bias, acc[tb][1] + bias,
                           acc[tb][2] + bias, acc[tb][3] + bias);
      }
    }
    // ---- attention, all in registers ----
    float csum = 0.f;
    #pragma unroll
    for (int tb = 0; tb < 4; ++tb){
      fvec4 p[4];
      #pragma unroll
      for (int sb = 0; sb < 4; ++sb)
        p[sb] = mfma16(kf8[sb], qf8[tb], fvec4{0.f, 0.f, 0.f, 0.f});
      // exp without rowmax: scores O(0.1); softmax shift-invariant -> exact
      float s = 0.f;
      #pragma unroll
      for (int sb = 0; sb < 4; ++sb)
        #pragma unroll
        for (int rg = 0; rg < 4; ++rg){
          float pv = exp2f(p[sb][rg]);
          p[sb][rg] = pv;
          s += pv;
        }
      s += __shfl_xor(s, 16);
      s += __shfl_xor(s, 32);
      float rinv = __builtin_amdgcn_rcpf(s);
      fvec4 o = fvec4{0.f, 0.f, 0.f, 0.f};
      #pragma unroll
      for (int sb = 0; sb < 4; ++sb){
        bvec8 pf = pack8z(p[sb][0] * rinv, p[sb][1] * rinv,
                          p[sb][2] * rinv, p[sb][3] * rinv);
        o = mfma16(pf, vf8[sb], o);
      }
      csum += o[0] + o[1] + o[2] + o[3];
    }
    csum += __shfl_xor(csum, 16);
    csum += __shfl_xor(csum, 32);
    if (g == 0 && l15 < 10)
      partials[(size_t)n * 120 + h * 10 + l15] = csum;
  }
}

// ---------------- deterministic reductions ----------------
__global__ void k_reduce(const float* __restrict__ partials, float* __restrict__ agg){
  __shared__ float red[256];
  int c = blockIdx.x, tid = threadIdx.x;
  float s = 0.f;
  for (int b = tid; b < NN; b += 256) s += partials[(size_t)b * 120 + c];
  red[tid] = s;
  __syncthreads();
  for (int st = 128; st > 0; st >>= 1){
    if (tid < st) red[tid] += red[tid + st];
    __syncthreads();
  }
  if (tid == 0) agg[c] = red[0] * (1.0f / (float)(NN * TT));
}

__global__ void k_final(const float* __restrict__ agg, const float* __restrict__ Wo,
                        const float* __restrict__ bo, float* __restrict__ out){
  __shared__ float r0[128], r1[128];
  int j = threadIdx.x;
  float a = (j < 120) ? agg[j] : 0.f;
  r0[j] = (j < 120) ? a * Wo[2 * j] : 0.f;
  r1[j] = (j < 120) ? a * Wo[2 * j + 1] : 0.f;
  __syncthreads();
  for (int st = 64; st > 0; st >>= 1){
    if (j < st){ r0[j] += r0[j + st]; r1[j] += r1[j + st]; }
    __syncthreads();
  }
  if (j == 0){ out[0] = r0[0] + bo[0]; out[1] = r1[0] + bo[1]; }
}

extern "C" void kernel_launch(void* const* d_in, const int* in_sizes, int n_in,
                              void* d_out, int out_size, void* d_ws, size_t ws_size,
                              hipStream_t stream){
  const int*   node_ids = (const int*)d_in[0];
  const int*   srcA     = (const int*)d_in[1];
  const int*   dstA     = (const int*)d_in[2];
  const float* ew       = (const float*)d_in[3];
  const float* emb      = (const float*)d_in[4];
  const float* Wp       = (const float*)d_in[5];
  const float* bp       = (const float*)d_in[6];
  const float* Wq       = (const float*)d_in[7];
  const float* bq       = (const float*)d_in[8];
  const float* Wk       = (const float*)d_in[9];
  const float* bk       = (const float*)d_in[10];
  const float* Wv       = (const float*)d_in[11];
  const float* bv       = (const float*)d_in[12];
  const float* Wo       = (const float*)d_in[13];
  const float* bo       = (const float*)d_in[14];

  char* p = (char*)d_ws;
  auto alloc = [&](size_t bytes) -> char* {
    char* r = p; p += (bytes + 255) & ~(size_t)255; return r;
  };
  // Total ~102.4 MB (proven footprint)
  uint16_t* xA    = (uint16_t*)alloc((size_t)TT * NN * DD * 2);
  uint16_t* xB    = (uint16_t*)alloc((size_t)TT * NN * DD * 2);
  int*      cnt   = (int*)alloc((size_t)TT * NN * 4);
  int*      esw   = (int*)alloc((size_t)TT * NN * 2 * CAP * 4);
  uint16_t* WpHi  = (uint16_t*)alloc(2048 * 8 * 2);
  uint16_t* WpLo  = (uint16_t*)alloc(2048 * 8 * 2);
  uint16_t* QHi   = (uint16_t*)alloc(9216 * 8 * 2);
  float*    biasP = (float*)alloc(576 * 4);
  float*    parts = (float*)alloc((size_t)NN * 120 * 4);
  float*    agg   = (float*)alloc(120 * 4);

  hipMemsetAsync(cnt, 0, (size_t)TT * NN * 4, stream);
  k_init<<<2048 + 47 + 8192, 256, 0, stream>>>(dstA, cnt, esw,
      Wp, Wq, Wk, Wv, bq, bk, bv, WpHi, WpLo, QHi, biasP,
      node_ids, emb, xA);
  k_sortconv<<<TT * NN / 256, 256, 0, stream>>>(cnt, esw, srcA, ew);
  k_prop<<<2048, 256, 0, stream>>>(xA, xB, cnt, esw, WpHi, WpLo, bp, 0);
  k_prop<<<2048, 256, 0, stream>>>(xB, xA, cnt, esw, WpHi, WpLo, bp, 0);
  k_prop<<<2048, 256, 0, stream>>>(xA, xB, cnt, esw, WpHi, WpLo, bp, 1);
  k_attn<<<NN, 256, 0, stream>>>(xB, QHi, biasP, parts);
  k_reduce<<<120, 256, 0, stream>>>(parts, agg);
  k_final<<<1, 128, 0, stream>>>(agg, Wo, bo, (float*)d_out);
}

// Round 15
// 241.959 us; speedup vs baseline: 1.8106x; 1.0892x over previous
//
#include <hip/hip_runtime.h>
#include <stdint.h>

#define TT 64
#define NN 2048
#define EE 8192
#define DD 128
#define CAP 32

typedef __attribute__((ext_vector_type(8))) short bvec8;
typedef __attribute__((ext_vector_type(4))) float fvec4;

__device__ __forceinline__ float bf2f(uint16_t u){
  union { uint32_t i; float f; } v; v.i = ((uint32_t)u) << 16; return v.f;
}
__device__ __forceinline__ float lo16(uint32_t u){
  union { uint32_t i; float f; } v; v.i = u << 16; return v.f;
}
__device__ __forceinline__ float hi16(uint32_t u){
  union { uint32_t i; float f; } v; v.i = u & 0xffff0000u; return v.f;
}
__device__ __forceinline__ uint16_t f2bf(float f){
  union { float f; uint32_t i; } v; v.f = f;
  uint32_t r = v.i + 0x7fffu + ((v.i >> 16) & 1u);
  return (uint16_t)(r >> 16);
}
// packed f32x2 -> bf16x2 (RNE), single VALU instr
__device__ __forceinline__ uint32_t cvtpk(float lo, float hi){
  uint32_t r;
  asm("v_cvt_pk_bf16_f32 %0, %1, %2" : "=v"(r) : "v"(lo), "v"(hi));
  return r;
}
__device__ __forceinline__ fvec4 mfma16(bvec8 a, bvec8 b, fvec4 c){
  return __builtin_amdgcn_mfma_f32_16x16x32_bf16(a, b, c, 0, 0, 0);
}
// 4 payload values in k-slots (g*8+0..3), zeros in slots 4..7. Both operands
// of a product use the same padding -> zero slots contribute exactly 0.
__device__ __forceinline__ bvec8 pack8z(float a, float b, float c, float d){
  union { uint32_t u[4]; bvec8 v; } r;
  r.u[0] = cvtpk(a, b);
  r.u[1] = cvtpk(c, d);
  r.u[2] = 0u;
  r.u[3] = 0u;
  return r.v;
}

// ---------------- merged init: CSR fill + weight prep + emb gather ----------------
// esw layout: per row, CAP interleaved (key/src, weight) int pairs.
__global__ void k_init(const int* __restrict__ dst, int* __restrict__ cnt,
                       int* __restrict__ esw,
                       const float* __restrict__ Wp, const float* __restrict__ Wq,
                       const float* __restrict__ Wk, const float* __restrict__ Wv,
                       const float* __restrict__ bq, const float* __restrict__ bk,
                       const float* __restrict__ bv,
                       uint16_t* __restrict__ WpHi, uint16_t* __restrict__ WpLo,
                       uint16_t* __restrict__ QHi, float* __restrict__ biasPad,
                       const int* __restrict__ ids, const float* __restrict__ emb,
                       uint16_t* __restrict__ x){
  int bid = blockIdx.x;
  if (bid < 2048){                                    // ---- fill (T*E threads)
    int tid = bid * 256 + threadIdx.x;
    int t = tid >> 13, e = tid & (EE - 1);
    int d = dst[tid];
    int row = t * NN + d;
    int pos = atomicAdd(&cnt[row], 1);
    if (pos < CAP) esw[(size_t)row * 2 * CAP + 2 * pos] = e;
  } else if (bid < 2048 + 47){                        // ---- weight prep
    int tid = (bid - 2048) * 256 + threadIdx.x;
    if (tid < 2048){
      int lane = tid & 63, kc = (tid >> 6) & 3, ct = tid >> 8;
      int g = lane >> 4, l15 = lane & 15;
      #pragma unroll
      for (int j = 0; j < 8; ++j){
        int k = kc * 32 + g * 8 + j;
        int col = ct * 16 + l15;
        float v = Wp[k * DD + col];
        uint16_t h = f2bf(v);
        WpHi[(size_t)tid * 8 + j] = h;
        WpLo[(size_t)tid * 8 + j] = f2bf(v - bf2f(h));
      }
    } else if (tid < 2048 + 9216){
      int idx = tid - 2048;
      int lane = idx & 63, kc = (idx >> 6) & 3, t2 = idx >> 8;  // t2 = m*12+h
      int h = t2 % 12, m = t2 / 12;
      const float* W = (m == 0) ? Wq : (m == 1) ? Wk : Wv;
      int g = lane >> 4, l15 = lane & 15;
      #pragma unroll
      for (int j = 0; j < 8; ++j){
        int k = kc * 32 + g * 8 + j;
        float v = (l15 < 10) ? W[k * 120 + h * 10 + l15] : 0.f;
        QHi[(size_t)idx * 8 + j] = f2bf(v);
      }
    } else if (tid < 2048 + 9216 + 576){
      int idx = tid - (2048 + 9216);
      int m = idx / 192, rest = idx % 192;
      int h = rest / 16, d = rest % 16;
      const float* B = (m == 0) ? bq : (m == 1) ? bk : bv;
      biasPad[idx] = (d < 10) ? B[h * 10 + d] : 0.f;
    }
  } else {                                            // ---- x0 = emb[ids] (T*N*16 threads)
    int tid = (bid - 2095) * 256 + threadIdx.x;
    int row = tid >> 4, c8 = tid & 15;
    int id = ids[row];
    const float* er = emb + (size_t)id * DD + c8 * 8;
    float4 a = *(const float4*)er;
    float4 b = *(const float4*)(er + 4);
    union { uint32_t u[4]; bvec8 v; } o;
    o.u[0] = cvtpk(a.x, a.y);
    o.u[1] = cvtpk(a.z, a.w);
    o.u[2] = cvtpk(b.x, b.y);
    o.u[3] = cvtpk(b.z, b.w);
    *(bvec8*)(x + (size_t)row * DD + c8 * 8) = o.v;
  }
}

// in-place: sort edge ids (stride-2 keys, deterministic), then convert to (src, weight)
__global__ void k_sortconv(int* __restrict__ cnt, int* __restrict__ esw,
                           const int* __restrict__ srcA, const float* __restrict__ ewA){
  int row = blockIdx.x * 256 + threadIdx.x;          // T*N threads
  if (row >= TT * NN) return;
  int t = row >> 11;
  int c = cnt[row]; if (c > CAP) c = CAP;
  cnt[row] = c;
  int* p = esw + (size_t)row * 2 * CAP;
  for (int i = 0; i < c; ++i){                        // selection sort ascending
    int mi = i, mv = p[2 * i];
    for (int j = i + 1; j < c; ++j){ int vj = p[2 * j]; if (vj < mv){ mv = vj; mi = j; } }
    if (mi != i){ p[2 * mi] = p[2 * i]; p[2 * i] = mv; }
  }
  const int* srcT = srcA + (size_t)t * EE;
  const float* ewT = ewA + (size_t)t * EE;
  for (int i = 0; i < c; ++i){
    int e = p[2 * i];
    p[2 * i]     = srcT[e];
    p[2 * i + 1] = __float_as_int(ewT[e]);
  }
}

// ---------------- fused propagate: n_hat = x + scatter; out = n_hat@Wp + bp ----------------
// 16-row blocks (grid 8192): each wave gathers only 4 rows, phase 2 is
// wave-per-2-column-tiles (acc[2]). CSR heads staged in LDS; 6 blocks/CU.
// r11-proven config (242.6 µs total); r12/r13 alternatives both worse.
__global__ __launch_bounds__(256, 6) void k_prop(const uint16_t* __restrict__ xin,
    uint16_t* __restrict__ xout, const int* __restrict__ cnt, const int* __restrict__ esw,
    const uint16_t* __restrict__ WHi, const uint16_t* __restrict__ WLo,
    const float* __restrict__ bp, int topt){
  __shared__ uint16_t lds[16 * 136];                  // 4352 B
  __shared__ int4 eplds[64];                          // 16 rows x first 8 (src,w) pairs
  int vb = blockIdx.x;
  int b = ((vb & 7) << 10) | (vb >> 3);               // XCD swizzle: 8 t-slices per XCD
  int t = b >> 7, n0 = (b & 127) << 4;
  int tid = threadIdx.x, w = tid >> 6, lane = tid & 63, g = lane >> 4, l15 = lane & 15;
  const uint16_t* xt = xin + (size_t)t * NN * DD;
  int baseRow = t * NN + n0;
  if (tid < 64)
    eplds[tid] = ((const int4*)(esw + (size_t)(baseRow + (tid >> 2)) * 2 * CAP))[tid & 3];
  int myc = (lane < 16) ? cnt[baseRow + lane] : 0;
  __syncthreads();
  // phase 1: 4 rows per wave, flat-8 predicated gather
  #pragma unroll 2
  for (int i = 0; i < 4; ++i){
    int r = w * 4 + i;
    int n = n0 + r;
    uint32_t u = *(const uint32_t*)(xt + (size_t)n * DD + (lane << 1));
    int c = __shfl(myc, r);                           // wave-uniform
    const int4* epr = &eplds[r * 4];                  // LDS broadcast reads
    int4 q0 = epr[0], q1 = epr[1], q2 = epr[2], q3 = epr[3];
    int sj[8]   = {q0.x, q0.z, q1.x, q1.z, q2.x, q2.z, q3.x, q3.z};
    float wj[8] = {__int_as_float(q0.y), __int_as_float(q0.w),
                   __int_as_float(q1.y), __int_as_float(q1.w),
                   __int_as_float(q2.y), __int_as_float(q2.w),
                   __int_as_float(q3.y), __int_as_float(q3.w)};
    uint32_t xs[8];
    float wf[8];
    #pragma unroll
    for (int j = 0; j < 8; ++j){
      int s = (j < c) ? sj[j] : 0;                    // clamp garbage idx, zero weight
      wf[j] = (j < c) ? wj[j] : 0.f;
      xs[j] = *(const uint32_t*)(xt + (size_t)s * DD + (lane << 1));
    }
    float a0 = lo16(u);
    float a1 = hi16(u);
    #pragma unroll
    for (int j = 0; j < 8; ++j){
      a0 = fmaf(wf[j], lo16(xs[j]), a0);
      a1 = fmaf(wf[j], hi16(xs[j]), a1);
    }
    if (c > 8){                                       // rare tail (P ~ 2%)
      int rowg = baseRow + r;
      for (int j = 8; j < c; ++j){
        int s = esw[(size_t)rowg * 2 * CAP + 2 * j];
        float wt = __int_as_float(esw[(size_t)rowg * 2 * CAP + 2 * j + 1]);
        uint32_t us = *(const uint32_t*)(xt + (size_t)s * DD + (lane << 1));
        a0 = fmaf(wt, lo16(us), a0);
        a1 = fmaf(wt, hi16(us), a1);
      }
    }
    *(uint32_t*)&lds[r * 136 + (lane << 1)] = cvtpk(a0, a1);
  }
  __syncthreads();
  // phase 2: GEMM [16x128] @ [128x128]; wave w -> column tiles 2w, 2w+1
  bvec8 afr[4];
  #pragma unroll
  for (int kc = 0; kc < 4; ++kc)
    afr[kc] = *(const bvec8*)&lds[l15 * 136 + kc * 32 + g * 8];
  fvec4 acc[2];
  acc[0] = fvec4{0.f, 0.f, 0.f, 0.f};
  acc[1] = fvec4{0.f, 0.f, 0.f, 0.f};
  #pragma unroll
  for (int kc = 0; kc < 4; ++kc){
    #pragma unroll
    for (int c2 = 0; c2 < 2; ++c2){
      int ct = w * 2 + c2;
      size_t base = ((size_t)(ct * 4 + kc) * 64 + lane) * 8;
      acc[c2] = mfma16(afr[kc], *(const bvec8*)&WHi[base], acc[c2]);
      acc[c2] = mfma16(afr[kc], *(const bvec8*)&WLo[base], acc[c2]);
    }
  }
  __syncthreads();
  // epilogue: C + bias -> bf16 back into LDS
  #pragma unroll
  for (int c2 = 0; c2 < 2; ++c2){
    int col = (w * 2 + c2) * 16 + l15;
    float bias = bp[col];
    uint32_t c01 = cvtpk(acc[c2][0] + bias, acc[c2][1] + bias);
    uint32_t c23 = cvtpk(acc[c2][2] + bias, acc[c2][3] + bias);
    int r = g * 4;
    lds[(r + 0) * 136 + col] = (uint16_t)c01;
    lds[(r + 1) * 136 + col] = (uint16_t)(c01 >> 16);
    lds[(r + 2) * 136 + col] = (uint16_t)c23;
    lds[(r + 3) * 136 + col] = (uint16_t)(c23 >> 16);
  }
  __syncthreads();
  // store (topt: last round writes [n][t][d] for attention)
  {
    int r = tid >> 4, c8 = tid & 15;
    bvec8 v = *(const bvec8*)&lds[r * 136 + c8 * 8];
    size_t dstoff;
    if (topt == 0) dstoff = ((size_t)t * NN + n0 + r) * DD + c8 * 8;
    else           dstoff = (((size_t)(n0 + r)) * TT + t) * DD + c8 * 8;
    *(bvec8*)(xout + dstoff) = v;
  }
}

// ---------------- fused QKV + attention + partial mean ----------------
// Head-per-wave; register-resident attention (zero-padded K=32 trick, r7-verified).
// Softmax scale folded into the Q pack (S' = CSC*S).
// NOTE: (256,3) is load-bearing — (256,4) squeezed VGPR 84->64 and spilled (r10).
// NOTE: in-block 3-pass loop is load-bearing — pass-per-block split NaN'd (r14).
__global__ __launch_bounds__(256, 3) void k_attn(const uint16_t* __restrict__ x3,
    const uint16_t* __restrict__ QHi, const float* __restrict__ biasPad,
    float* __restrict__ partials){
  __shared__ uint16_t seq[64 * 136];                  // 17408 B
  int n = blockIdx.x;
  int tid = threadIdx.x, w = tid >> 6, lane = tid & 63, g = lane >> 4, l15 = lane & 15;
  const uint16_t* xr = x3 + (size_t)n * TT * DD;
  #pragma unroll
  for (int p4 = 0; p4 < 4; ++p4){
    int chunk = p4 * 256 + tid, r = chunk >> 4, c8 = chunk & 15;
    *(bvec8*)&seq[r * 136 + c8 * 8] = *(const bvec8*)&xr[r * 128 + c8 * 8];
  }
  __syncthreads();                                    // the only barrier

  const float CSC = 0.31622776601683794f * 1.4426950408889634f;  // (1/sqrt(10))*log2(e)

  for (int pass = 0; pass < 3; ++pass){
    int h = pass * 4 + w;
    bvec8 qf8[4], kf8[4], vf8[4];
    #pragma unroll
    for (int m = 0; m < 3; ++m){
      fvec4 acc[4];
      #pragma unroll
      for (int i = 0; i < 4; ++i) acc[i] = fvec4{0.f, 0.f, 0.f, 0.f};
      #pragma unroll
      for (int kc = 0; kc < 4; ++kc){
        bvec8 B = *(const bvec8*)&QHi[((size_t)((m * 12 + h) * 4 + kc) * 64 + lane) * 8];
        #pragma unroll
        for (int tb = 0; tb < 4; ++tb){
          bvec8 a = *(const bvec8*)&seq[(tb * 16 + l15) * 136 + kc * 32 + g * 8];
          if (m == 2) acc[tb] = mfma16(a, B, acc[tb]);  // V: lane=d, regs=s
          else        acc[tb] = mfma16(B, a, acc[tb]);  // Q,K: lane=t, regs=d
        }
      }
      if (m == 0){                                     // Q: fold softmax scale
        float4 b4 = *(const float4*)&biasPad[(0 * 12 + h) * 16 + g * 4];
        #pragma unroll
        for (int tb = 0; tb < 4; ++tb)
          qf8[tb] = pack8z((acc[tb][0] + b4.x) * CSC, (acc[tb][1] + b4.y) * CSC,
                           (acc[tb][2] + b4.z) * CSC, (acc[tb][3] + b4.w) * CSC);
      } else if (m == 1){
        float4 b4 = *(const float4*)&biasPad[(1 * 12 + h) * 16 + g * 4];
        #pragma unroll
        for (int tb = 0; tb < 4; ++tb)
          kf8[tb] = pack8z(acc[tb][0] + b4.x, acc[tb][1] + b4.y,
                           acc[tb][2] + b4.z, acc[tb][3] + b4.w);
      } else {
        float bias = biasPad[(2 * 12 + h) * 16 + l15];  // per-d bias (lane=d)
        #pragma unroll
        for (int tb = 0; tb < 4; ++tb)
          vf8[tb] = pack8z(acc[tb][0] + bias, acc[tb][1] + bias,
                           acc[tb][2] + bias, acc[tb][3] + bias);
      }
    }
    // ---- attention, all in registers ----
    float csum = 0.f;
    #pragma unroll
    for (int tb = 0; tb < 4; ++tb){
      fvec4 p[4];
      #pragma unroll
      for (int sb = 0; sb < 4; ++sb)
        p[sb] = mfma16(kf8[sb], qf8[tb], fvec4{0.f, 0.f, 0.f, 0.f});
      // exp without rowmax: scores O(0.1); softmax shift-invariant -> exact
      float s = 0.f;
      #pragma unroll
      for (int sb = 0; sb < 4; ++sb)
        #pragma unroll
        for (int rg = 0; rg < 4; ++rg){
          float pv = exp2f(p[sb][rg]);
          p[sb][rg] = pv;
          s += pv;
        }
      s += __shfl_xor(s, 16);
      s += __shfl_xor(s, 32);
      float rinv = __builtin_amdgcn_rcpf(s);
      fvec4 o = fvec4{0.f, 0.f, 0.f, 0.f};
      #pragma unroll
      for (int sb = 0; sb < 4; ++sb){
        bvec8 pf = pack8z(p[sb][0] * rinv, p[sb][1] * rinv,
                          p[sb][2] * rinv, p[sb][3] * rinv);
        o = mfma16(pf, vf8[sb], o);
      }
      csum += o[0] + o[1] + o[2] + o[3];
    }
    csum += __shfl_xor(csum, 16);
    csum += __shfl_xor(csum, 32);
    if (g == 0 && l15 < 10)
      partials[(size_t)n * 120 + h * 10 + l15] = csum;
  }
}

// ---------------- deterministic reductions ----------------
__global__ void k_reduce(const float* __restrict__ partials, float* __restrict__ agg){
  __shared__ float red[256];
  int c = blockIdx.x, tid = threadIdx.x;
  float s = 0.f;
  for (int b = tid; b < NN; b += 256) s += partials[(size_t)b * 120 + c];
  red[tid] = s;
  __syncthreads();
  for (int st = 128; st > 0; st >>= 1){
    if (tid < st) red[tid] += red[tid + st];
    __syncthreads();
  }
  if (tid == 0) agg[c] = red[0] * (1.0f / (float)(NN * TT));
}

__global__ void k_final(const float* __restrict__ agg, const float* __restrict__ Wo,
                        const float* __restrict__ bo, float* __restrict__ out){
  __shared__ float r0[128], r1[128];
  int j = threadIdx.x;
  float a = (j < 120) ? agg[j] : 0.f;
  r0[j] = (j < 120) ? a * Wo[2 * j] : 0.f;
  r1[j] = (j < 120) ? a * Wo[2 * j + 1] : 0.f;
  __syncthreads();
  for (int st = 64; st > 0; st >>= 1){
    if (j < st){ r0[j] += r0[j + st]; r1[j] += r1[j + st]; }
    __syncthreads();
  }
  if (j == 0){ out[0] = r0[0] + bo[0]; out[1] = r1[0] + bo[1]; }
}

extern "C" void kernel_launch(void* const* d_in, const int* in_sizes, int n_in,
                              void* d_out, int out_size, void* d_ws, size_t ws_size,
                              hipStream_t stream){
  const int*   node_ids = (const int*)d_in[0];
  const int*   srcA     = (const int*)d_in[1];
  const int*   dstA     = (const int*)d_in[2];
  const float* ew       = (const float*)d_in[3];
  const float* emb      = (const float*)d_in[4];
  const float* Wp       = (const float*)d_in[5];
  const float* bp       = (const float*)d_in[6];
  const float* Wq       = (const float*)d_in[7];
  const float* bq       = (const float*)d_in[8];
  const float* Wk       = (const float*)d_in[9];
  const float* bk       = (const float*)d_in[10];
  const float* Wv       = (const float*)d_in[11];
  const float* bv       = (const float*)d_in[12];
  const float* Wo       = (const float*)d_in[13];
  const float* bo       = (const float*)d_in[14];

  char* p = (char*)d_ws;
  auto alloc = [&](size_t bytes) -> char* {
    char* r = p; p += (bytes + 255) & ~(size_t)255; return r;
  };
  // Total ~102.4 MB (proven footprint)
  uint16_t* xA    = (uint16_t*)alloc((size_t)TT * NN * DD * 2);
  uint16_t* xB    = (uint16_t*)alloc((size_t)TT * NN * DD * 2);
  int*      cnt   = (int*)alloc((size_t)TT * NN * 4);
  int*      esw   = (int*)alloc((size_t)TT * NN * 2 * CAP * 4);
  uint16_t* WpHi  = (uint16_t*)alloc(2048 * 8 * 2);
  uint16_t* WpLo  = (uint16_t*)alloc(2048 * 8 * 2);
  uint16_t* QHi   = (uint16_t*)alloc(9216 * 8 * 2);
  float*    biasP = (float*)alloc(576 * 4);
  float*    parts = (float*)alloc((size_t)NN * 120 * 4);
  float*    agg   = (float*)alloc(120 * 4);

  hipMemsetAsync(cnt, 0, (size_t)TT * NN * 4, stream);
  k_init<<<2048 + 47 + 8192, 256, 0, stream>>>(dstA, cnt, esw,
      Wp, Wq, Wk, Wv, bq, bk, bv, WpHi, WpLo, QHi, biasP,
      node_ids, emb, xA);
  k_sortconv<<<TT * NN / 256, 256, 0, stream>>>(cnt, esw, srcA, ew);
  k_prop<<<8192, 256, 0, stream>>>(xA, xB, cnt, esw, WpHi, WpLo, bp, 0);
  k_prop<<<8192, 256, 0, stream>>>(xB, xA, cnt, esw, WpHi, WpLo, bp, 0);
  k_prop<<<8192, 256, 0, stream>>>(xA, xB, cnt, esw, WpHi, WpLo, bp, 1);
  k_attn<<<NN, 256, 0, stream>>>(xB, QHi, biasP, parts);
  k_reduce<<<120, 256, 0, stream>>>(parts, agg);
  k_final<<<1, 128, 0, stream>>>(agg, Wo, bo, (float*)d_out);
}

// Round 16
// 240.821 us; speedup vs baseline: 1.8191x; 1.0047x over previous
//
#include <hip/hip_runtime.h>
#include <stdint.h>

#define TT 64
#define NN 2048
#define EE 8192
#define DD 128
#define CAP 32

typedef __attribute__((ext_vector_type(8))) short bvec8;
typedef __attribute__((ext_vector_type(4))) float fvec4;

__device__ __forceinline__ float bf2f(uint16_t u){
  union { uint32_t i; float f; } v; v.i = ((uint32_t)u) << 16; return v.f;
}
__device__ __forceinline__ float lo16(uint32_t u){
  union { uint32_t i; float f; } v; v.i = u << 16; return v.f;
}
__device__ __forceinline__ float hi16(uint32_t u){
  union { uint32_t i; float f; } v; v.i = u & 0xffff0000u; return v.f;
}
__device__ __forceinline__ uint16_t f2bf(float f){
  union { float f; uint32_t i; } v; v.f = f;
  uint32_t r = v.i + 0x7fffu + ((v.i >> 16) & 1u);
  return (uint16_t)(r >> 16);
}
// packed f32x2 -> bf16x2 (RNE), single VALU instr
__device__ __forceinline__ uint32_t cvtpk(float lo, float hi){
  uint32_t r;
  asm("v_cvt_pk_bf16_f32 %0, %1, %2" : "=v"(r) : "v"(lo), "v"(hi));
  return r;
}
__device__ __forceinline__ fvec4 mfma16(bvec8 a, bvec8 b, fvec4 c){
  return __builtin_amdgcn_mfma_f32_16x16x32_bf16(a, b, c, 0, 0, 0);
}
// 4 payload values in k-slots (g*8+0..3), zeros in slots 4..7. Both operands
// of a product use the same padding -> zero slots contribute exactly 0.
__device__ __forceinline__ bvec8 pack8z(float a, float b, float c, float d){
  union { uint32_t u[4]; bvec8 v; } r;
  r.u[0] = cvtpk(a, b);
  r.u[1] = cvtpk(c, d);
  r.u[2] = 0u;
  r.u[3] = 0u;
  return r.v;
}

// ---------------- merged init: CSR fill + weight prep + emb gather ----------------
// esw layout: per row, CAP interleaved (key/src, weight) int pairs.
__global__ void k_init(const int* __restrict__ dst, int* __restrict__ cnt,
                       int* __restrict__ esw,
                       const float* __restrict__ Wp, const float* __restrict__ Wq,
                       const float* __restrict__ Wk, const float* __restrict__ Wv,
                       const float* __restrict__ bq, const float* __restrict__ bk,
                       const float* __restrict__ bv,
                       uint16_t* __restrict__ WpHi, uint16_t* __restrict__ WpLo,
                       uint16_t* __restrict__ QHi, float* __restrict__ biasPad,
                       const int* __restrict__ ids, const float* __restrict__ emb,
                       uint16_t* __restrict__ x){
  int bid = blockIdx.x;
  if (bid < 2048){                                    // ---- fill (T*E threads)
    int tid = bid * 256 + threadIdx.x;
    int t = tid >> 13, e = tid & (EE - 1);
    int d = dst[tid];
    int row = t * NN + d;
    int pos = atomicAdd(&cnt[row], 1);
    if (pos < CAP) esw[(size_t)row * 2 * CAP + 2 * pos] = e;
  } else if (bid < 2048 + 47){                        // ---- weight prep
    int tid = (bid - 2048) * 256 + threadIdx.x;
    if (tid < 2048){
      int lane = tid & 63, kc = (tid >> 6) & 3, ct = tid >> 8;
      int g = lane >> 4, l15 = lane & 15;
      #pragma unroll
      for (int j = 0; j < 8; ++j){
        int k = kc * 32 + g * 8 + j;
        int col = ct * 16 + l15;
        float v = Wp[k * DD + col];
        uint16_t h = f2bf(v);
        WpHi[(size_t)tid * 8 + j] = h;
        WpLo[(size_t)tid * 8 + j] = f2bf(v - bf2f(h));
      }
    } else if (tid < 2048 + 9216){
      int idx = tid - 2048;
      int lane = idx & 63, kc = (idx >> 6) & 3, t2 = idx >> 8;  // t2 = m*12+h
      int h = t2 % 12, m = t2 / 12;
      const float* W = (m == 0) ? Wq : (m == 1) ? Wk : Wv;
      int g = lane >> 4, l15 = lane & 15;
      #pragma unroll
      for (int j = 0; j < 8; ++j){
        int k = kc * 32 + g * 8 + j;
        float v = (l15 < 10) ? W[k * 120 + h * 10 + l15] : 0.f;
        QHi[(size_t)idx * 8 + j] = f2bf(v);
      }
    } else if (tid < 2048 + 9216 + 576){
      int idx = tid - (2048 + 9216);
      int m = idx / 192, rest = idx % 192;
      int h = rest / 16, d = rest % 16;
      const float* B = (m == 0) ? bq : (m == 1) ? bk : bv;
      biasPad[idx] = (d < 10) ? B[h * 10 + d] : 0.f;
    }
  } else {                                            // ---- x0 = emb[ids] (T*N*16 threads)
    int tid = (bid - 2095) * 256 + threadIdx.x;
    int row = tid >> 4, c8 = tid & 15;
    int id = ids[row];
    const float* er = emb + (size_t)id * DD + c8 * 8;
    float4 a = *(const float4*)er;
    float4 b = *(const float4*)(er + 4);
    union { uint32_t u[4]; bvec8 v; } o;
    o.u[0] = cvtpk(a.x, a.y);
    o.u[1] = cvtpk(a.z, a.w);
    o.u[2] = cvtpk(b.x, b.y);
    o.u[3] = cvtpk(b.z, b.w);
    *(bvec8*)(x + (size_t)row * DD + c8 * 8) = o.v;
  }
}

// in-place: sort edge ids (stride-2 keys, deterministic), then convert to (src, weight)
__global__ void k_sortconv(int* __restrict__ cnt, int* __restrict__ esw,
                           const int* __restrict__ srcA, const float* __restrict__ ewA){
  int row = blockIdx.x * 256 + threadIdx.x;          // T*N threads
  if (row >= TT * NN) return;
  int t = row >> 11;
  int c = cnt[row]; if (c > CAP) c = CAP;
  cnt[row] = c;
  int* p = esw + (size_t)row * 2 * CAP;
  for (int i = 0; i < c; ++i){                        // selection sort ascending
    int mi = i, mv = p[2 * i];
    for (int j = i + 1; j < c; ++j){ int vj = p[2 * j]; if (vj < mv){ mv = vj; mi = j; } }
    if (mi != i){ p[2 * mi] = p[2 * i]; p[2 * i] = mv; }
  }
  const int* srcT = srcA + (size_t)t * EE;
  const float* ewT = ewA + (size_t)t * EE;
  for (int i = 0; i < c; ++i){
    int e = p[2 * i];
    p[2 * i]     = srcT[e];
    p[2 * i + 1] = __float_as_int(ewT[e]);
  }
}

// ---------------- fused propagate: n_hat = x + scatter; out = n_hat@Wp + bp ----------------
// 16-row blocks (grid 8192): each wave gathers only 4 rows, phase 2 is
// wave-per-2-column-tiles (acc[2]). CSR heads staged in LDS; 6 blocks/CU.
// r11-proven config; r12/r13 alternatives both worse.
__global__ __launch_bounds__(256, 6) void k_prop(const uint16_t* __restrict__ xin,
    uint16_t* __restrict__ xout, const int* __restrict__ cnt, const int* __restrict__ esw,
    const uint16_t* __restrict__ WHi, const uint16_t* __restrict__ WLo,
    const float* __restrict__ bp, int topt){
  __shared__ uint16_t lds[16 * 136];                  // 4352 B
  __shared__ int4 eplds[64];                          // 16 rows x first 8 (src,w) pairs
  int vb = blockIdx.x;
  int b = ((vb & 7) << 10) | (vb >> 3);               // XCD swizzle: 8 t-slices per XCD
  int t = b >> 7, n0 = (b & 127) << 4;
  int tid = threadIdx.x, w = tid >> 6, lane = tid & 63, g = lane >> 4, l15 = lane & 15;
  const uint16_t* xt = xin + (size_t)t * NN * DD;
  int baseRow = t * NN + n0;
  if (tid < 64)
    eplds[tid] = ((const int4*)(esw + (size_t)(baseRow + (tid >> 2)) * 2 * CAP))[tid & 3];
  int myc = (lane < 16) ? cnt[baseRow + lane] : 0;
  __syncthreads();
  // phase 1: 4 rows per wave, flat-8 predicated gather
  #pragma unroll 2
  for (int i = 0; i < 4; ++i){
    int r = w * 4 + i;
    int n = n0 + r;
    uint32_t u = *(const uint32_t*)(xt + (size_t)n * DD + (lane << 1));
    int c = __shfl(myc, r);                           // wave-uniform
    const int4* epr = &eplds[r * 4];                  // LDS broadcast reads
    int4 q0 = epr[0], q1 = epr[1], q2 = epr[2], q3 = epr[3];
    int sj[8]   = {q0.x, q0.z, q1.x, q1.z, q2.x, q2.z, q3.x, q3.z};
    float wj[8] = {__int_as_float(q0.y), __int_as_float(q0.w),
                   __int_as_float(q1.y), __int_as_float(q1.w),
                   __int_as_float(q2.y), __int_as_float(q2.w),
                   __int_as_float(q3.y), __int_as_float(q3.w)};
    uint32_t xs[8];
    float wf[8];
    #pragma unroll
    for (int j = 0; j < 8; ++j){
      int s = (j < c) ? sj[j] : 0;                    // clamp garbage idx, zero weight
      wf[j] = (j < c) ? wj[j] : 0.f;
      xs[j] = *(const uint32_t*)(xt + (size_t)s * DD + (lane << 1));
    }
    float a0 = lo16(u);
    float a1 = hi16(u);
    #pragma unroll
    for (int j = 0; j < 8; ++j){
      a0 = fmaf(wf[j], lo16(xs[j]), a0);
      a1 = fmaf(wf[j], hi16(xs[j]), a1);
    }
    if (c > 8){                                       // rare tail (P ~ 2%)
      int rowg = baseRow + r;
      for (int j = 8; j < c; ++j){
        int s = esw[(size_t)rowg * 2 * CAP + 2 * j];
        float wt = __int_as_float(esw[(size_t)rowg * 2 * CAP + 2 * j + 1]);
        uint32_t us = *(const uint32_t*)(xt + (size_t)s * DD + (lane << 1));
        a0 = fmaf(wt, lo16(us), a0);
        a1 = fmaf(wt, hi16(us), a1);
      }
    }
    *(uint32_t*)&lds[r * 136 + (lane << 1)] = cvtpk(a0, a1);
  }
  __syncthreads();
  // phase 2: GEMM [16x128] @ [128x128]; wave w -> column tiles 2w, 2w+1
  bvec8 afr[4];
  #pragma unroll
  for (int kc = 0; kc < 4; ++kc)
    afr[kc] = *(const bvec8*)&lds[l15 * 136 + kc * 32 + g * 8];
  fvec4 acc[2];
  acc[0] = fvec4{0.f, 0.f, 0.f, 0.f};
  acc[1] = fvec4{0.f, 0.f, 0.f, 0.f};
  #pragma unroll
  for (int kc = 0; kc < 4; ++kc){
    #pragma unroll
    for (int c2 = 0; c2 < 2; ++c2){
      int ct = w * 2 + c2;
      size_t base = ((size_t)(ct * 4 + kc) * 64 + lane) * 8;
      acc[c2] = mfma16(afr[kc], *(const bvec8*)&WHi[base], acc[c2]);
      acc[c2] = mfma16(afr[kc], *(const bvec8*)&WLo[base], acc[c2]);
    }
  }
  __syncthreads();
  // epilogue: C + bias -> bf16 back into LDS
  #pragma unroll
  for (int c2 = 0; c2 < 2; ++c2){
    int col = (w * 2 + c2) * 16 + l15;
    float bias = bp[col];
    uint32_t c01 = cvtpk(acc[c2][0] + bias, acc[c2][1] + bias);
    uint32_t c23 = cvtpk(acc[c2][2] + bias, acc[c2][3] + bias);
    int r = g * 4;
    lds[(r + 0) * 136 + col] = (uint16_t)c01;
    lds[(r + 1) * 136 + col] = (uint16_t)(c01 >> 16);
    lds[(r + 2) * 136 + col] = (uint16_t)c23;
    lds[(r + 3) * 136 + col] = (uint16_t)(c23 >> 16);
  }
  __syncthreads();
  // store (topt: last round writes [n][t][d] for attention)
  {
    int r = tid >> 4, c8 = tid & 15;
    bvec8 v = *(const bvec8*)&lds[r * 136 + c8 * 8];
    size_t dstoff;
    if (topt == 0) dstoff = ((size_t)t * NN + n0 + r) * DD + c8 * 8;
    else           dstoff = (((size_t)(n0 + r)) * TT + t) * DD + c8 * 8;
    *(bvec8*)(xout + dstoff) = v;
  }
}

// ---------------- fused QKV + attention + partial mean ----------------
// Head-per-wave; register-resident attention (zero-padded K=32 trick, r7-verified).
// Softmax scale folded into the Q pack; normalization DEFERRED past PV:
// csum += (sum o)*rinv  ==  sum (P/s)·V — takes shuffle+rcp+16 muls off the
// S->PV MFMA critical path.
// NOTE: (256,3) is load-bearing — (256,4) squeezed VGPR 84->64 and spilled (r10).
// NOTE: in-block 3-pass loop is load-bearing — pass-per-block split NaN'd (r14).
__global__ __launch_bounds__(256, 3) void k_attn(const uint16_t* __restrict__ x3,
    const uint16_t* __restrict__ QHi, const float* __restrict__ biasPad,
    float* __restrict__ partials){
  __shared__ uint16_t seq[64 * 136];                  // 17408 B
  int n = blockIdx.x;
  int tid = threadIdx.x, w = tid >> 6, lane = tid & 63, g = lane >> 4, l15 = lane & 15;
  const uint16_t* xr = x3 + (size_t)n * TT * DD;
  #pragma unroll
  for (int p4 = 0; p4 < 4; ++p4){
    int chunk = p4 * 256 + tid, r = chunk >> 4, c8 = chunk & 15;
    *(bvec8*)&seq[r * 136 + c8 * 8] = *(const bvec8*)&xr[r * 128 + c8 * 8];
  }
  __syncthreads();                                    // the only barrier

  const float CSC = 0.31622776601683794f * 1.4426950408889634f;  // (1/sqrt(10))*log2(e)

  for (int pass = 0; pass < 3; ++pass){
    int h = pass * 4 + w;
    bvec8 qf8[4], kf8[4], vf8[4];
    #pragma unroll
    for (int m = 0; m < 3; ++m){
      fvec4 acc[4];
      #pragma unroll
      for (int i = 0; i < 4; ++i) acc[i] = fvec4{0.f, 0.f, 0.f, 0.f};
      #pragma unroll
      for (int kc = 0; kc < 4; ++kc){
        bvec8 B = *(const bvec8*)&QHi[((size_t)((m * 12 + h) * 4 + kc) * 64 + lane) * 8];
        #pragma unroll
        for (int tb = 0; tb < 4; ++tb){
          bvec8 a = *(const bvec8*)&seq[(tb * 16 + l15) * 136 + kc * 32 + g * 8];
          if (m == 2) acc[tb] = mfma16(a, B, acc[tb]);  // V: lane=d, regs=s
          else        acc[tb] = mfma16(B, a, acc[tb]);  // Q,K: lane=t, regs=d
        }
      }
      if (m == 0){                                     // Q: fold softmax scale
        float4 b4 = *(const float4*)&biasPad[(0 * 12 + h) * 16 + g * 4];
        #pragma unroll
        for (int tb = 0; tb < 4; ++tb)
          qf8[tb] = pack8z((acc[tb][0] + b4.x) * CSC, (acc[tb][1] + b4.y) * CSC,
                           (acc[tb][2] + b4.z) * CSC, (acc[tb][3] + b4.w) * CSC);
      } else if (m == 1){
        float4 b4 = *(const float4*)&biasPad[(1 * 12 + h) * 16 + g * 4];
        #pragma unroll
        for (int tb = 0; tb < 4; ++tb)
          kf8[tb] = pack8z(acc[tb][0] + b4.x, acc[tb][1] + b4.y,
                           acc[tb][2] + b4.z, acc[tb][3] + b4.w);
      } else {
        float bias = biasPad[(2 * 12 + h) * 16 + l15];  // per-d bias (lane=d)
        #pragma unroll
        for (int tb = 0; tb < 4; ++tb)
          vf8[tb] = pack8z(acc[tb][0] + bias, acc[tb][1] + bias,
                           acc[tb][2] + bias, acc[tb][3] + bias);
      }
    }
    // ---- attention, all in registers ----
    float csum = 0.f;
    #pragma unroll
    for (int tb = 0; tb < 4; ++tb){
      fvec4 p[4];
      #pragma unroll
      for (int sb = 0; sb < 4; ++sb)
        p[sb] = mfma16(kf8[sb], qf8[tb], fvec4{0.f, 0.f, 0.f, 0.f});
      // exp without rowmax: scores O(0.1); softmax shift-invariant -> exact
      float s = 0.f;
      #pragma unroll
      for (int sb = 0; sb < 4; ++sb)
        #pragma unroll
        for (int rg = 0; rg < 4; ++rg){
          float pv = exp2f(p[sb][rg]);
          p[sb][rg] = pv;
          s += pv;
        }
      // PV on UNNORMALIZED P (bounded ~1.1); normalization deferred to csum.
      fvec4 o = fvec4{0.f, 0.f, 0.f, 0.f};
      #pragma unroll
      for (int sb = 0; sb < 4; ++sb){
        bvec8 pf = pack8z(p[sb][0], p[sb][1], p[sb][2], p[sb][3]);
        o = mfma16(pf, vf8[sb], o);
      }
      s += __shfl_xor(s, 16);
      s += __shfl_xor(s, 32);
      float rinv = __builtin_amdgcn_rcpf(s);
      csum += (o[0] + o[1] + o[2] + o[3]) * rinv;
    }
    csum += __shfl_xor(csum, 16);
    csum += __shfl_xor(csum, 32);
    if (g == 0 && l15 < 10)
      partials[(size_t)n * 120 + h * 10 + l15] = csum;
  }
}

// ---------------- deterministic reductions ----------------
__global__ void k_reduce(const float* __restrict__ partials, float* __restrict__ agg){
  __shared__ float red[256];
  int c = blockIdx.x, tid = threadIdx.x;
  float s = 0.f;
  for (int b = tid; b < NN; b += 256) s += partials[(size_t)b * 120 + c];
  red[tid] = s;
  __syncthreads();
  for (int st = 128; st > 0; st >>= 1){
    if (tid < st) red[tid] += red[tid + st];
    __syncthreads();
  }
  if (tid == 0) agg[c] = red[0] * (1.0f / (float)(NN * TT));
}

__global__ void k_final(const float* __restrict__ agg, const float* __restrict__ Wo,
                        const float* __restrict__ bo, float* __restrict__ out){
  __shared__ float r0[128], r1[128];
  int j = threadIdx.x;
  float a = (j < 120) ? agg[j] : 0.f;
  r0[j] = (j < 120) ? a * Wo[2 * j] : 0.f;
  r1[j] = (j < 120) ? a * Wo[2 * j + 1] : 0.f;
  __syncthreads();
  for (int st = 64; st > 0; st >>= 1){
    if (j < st){ r0[j] += r0[j + st]; r1[j] += r1[j + st]; }
    __syncthreads();
  }
  if (j == 0){ out[0] = r0[0] + bo[0]; out[1] = r1[0] + bo[1]; }
}

extern "C" void kernel_launch(void* const* d_in, const int* in_sizes, int n_in,
                              void* d_out, int out_size, void* d_ws, size_t ws_size,
                              hipStream_t stream){
  const int*   node_ids = (const int*)d_in[0];
  const int*   srcA     = (const int*)d_in[1];
  const int*   dstA     = (const int*)d_in[2];
  const float* ew       = (const float*)d_in[3];
  const float* emb      = (const float*)d_in[4];
  const float* Wp       = (const float*)d_in[5];
  const float* bp       = (const float*)d_in[6];
  const float* Wq       = (const float*)d_in[7];
  const float* bq       = (const float*)d_in[8];
  const float* Wk       = (const float*)d_in[9];
  const float* bk       = (const float*)d_in[10];
  const float* Wv       = (const float*)d_in[11];
  const float* bv       = (const float*)d_in[12];
  const float* Wo       = (const float*)d_in[13];
  const float* bo       = (const float*)d_in[14];

  char* p = (char*)d_ws;
  auto alloc = [&](size_t bytes) -> char* {
    char* r = p; p += (bytes + 255) & ~(size_t)255; return r;
  };
  // Total ~102.4 MB (proven footprint)
  uint16_t* xA    = (uint16_t*)alloc((size_t)TT * NN * DD * 2);
  uint16_t* xB    = (uint16_t*)alloc((size_t)TT * NN * DD * 2);
  int*      cnt   = (int*)alloc((size_t)TT * NN * 4);
  int*      esw   = (int*)alloc((size_t)TT * NN * 2 * CAP * 4);
  uint16_t* WpHi  = (uint16_t*)alloc(2048 * 8 * 2);
  uint16_t* WpLo  = (uint16_t*)alloc(2048 * 8 * 2);
  uint16_t* QHi   = (uint16_t*)alloc(9216 * 8 * 2);
  float*    biasP = (float*)alloc(576 * 4);
  float*    parts = (float*)alloc((size_t)NN * 120 * 4);
  float*    agg   = (float*)alloc(120 * 4);

  hipMemsetAsync(cnt, 0, (size_t)TT * NN * 4, stream);
  k_init<<<2048 + 47 + 8192, 256, 0, stream>>>(dstA, cnt, esw,
      Wp, Wq, Wk, Wv, bq, bk, bv, WpHi, WpLo, QHi, biasP,
      node_ids, emb, xA);
  k_sortconv<<<TT * NN / 256, 256, 0, stream>>>(cnt, esw, srcA, ew);
  k_prop<<<8192, 256, 0, stream>>>(xA, xB, cnt, esw, WpHi, WpLo, bp, 0);
  k_prop<<<8192, 256, 0, stream>>>(xB, xA, cnt, esw, WpHi, WpLo, bp, 0);
  k_prop<<<8192, 256, 0, stream>>>(xA, xB, cnt, esw, WpHi, WpLo, bp, 1);
  k_attn<<<NN, 256, 0, stream>>>(xB, QHi, biasP, parts);
  k_reduce<<<120, 256, 0, stream>>>(parts, agg);
  k_final<<<1, 128, 0, stream>>>(agg, Wo, bo, (float*)d_out);
}

// Round 17
// 238.374 us; speedup vs baseline: 1.8378x; 1.0103x over previous
//
#include <hip/hip_runtime.h>
#include <stdint.h>

#define TT 64
#define NN 2048
#define EE 8192
#define DD 128
#define CAP 32

typedef __attribute__((ext_vector_type(8))) short bvec8;
typedef __attribute__((ext_vector_type(4))) float fvec4;

__device__ __forceinline__ float bf2f(uint16_t u){
  union { uint32_t i; float f; } v; v.i = ((uint32_t)u) << 16; return v.f;
}
__device__ __forceinline__ float lo16(uint32_t u){
  union { uint32_t i; float f; } v; v.i = u << 16; return v.f;
}
__device__ __forceinline__ float hi16(uint32_t u){
  union { uint32_t i; float f; } v; v.i = u & 0xffff0000u; return v.f;
}
__device__ __forceinline__ uint16_t f2bf(float f){
  union { float f; uint32_t i; } v; v.f = f;
  uint32_t r = v.i + 0x7fffu + ((v.i >> 16) & 1u);
  return (uint16_t)(r >> 16);
}
// packed f32x2 -> bf16x2 (RNE), single VALU instr
__device__ __forceinline__ uint32_t cvtpk(float lo, float hi){
  uint32_t r;
  asm("v_cvt_pk_bf16_f32 %0, %1, %2" : "=v"(r) : "v"(lo), "v"(hi));
  return r;
}
__device__ __forceinline__ fvec4 mfma16(bvec8 a, bvec8 b, fvec4 c){
  return __builtin_amdgcn_mfma_f32_16x16x32_bf16(a, b, c, 0, 0, 0);
}
// 4 payload values in k-slots (g*8+0..3), zeros in slots 4..7. Both operands
// of a product use the same padding -> zero slots contribute exactly 0.
__device__ __forceinline__ bvec8 pack8z(float a, float b, float c, float d){
  union { uint32_t u[4]; bvec8 v; } r;
  r.u[0] = cvtpk(a, b);
  r.u[1] = cvtpk(c, d);
  r.u[2] = 0u;
  r.u[3] = 0u;
  return r.v;
}

// ---------------- merged init: CSR fill + weight prep + emb gather ----------------
// esw layout: per row, CAP interleaved (key/src, weight) int pairs.
__global__ void k_init(const int* __restrict__ dst, int* __restrict__ cnt,
                       int* __restrict__ esw,
                       const float* __restrict__ Wp, const float* __restrict__ Wq,
                       const float* __restrict__ Wk, const float* __restrict__ Wv,
                       const float* __restrict__ bq, const float* __restrict__ bk,
                       const float* __restrict__ bv,
                       uint16_t* __restrict__ WpHi, uint16_t* __restrict__ WpLo,
                       uint16_t* __restrict__ QHi, float* __restrict__ biasPad,
                       const int* __restrict__ ids, const float* __restrict__ emb,
                       uint16_t* __restrict__ x){
  int bid = blockIdx.x;
  if (bid < 2048){                                    // ---- fill (T*E threads)
    int tid = bid * 256 + threadIdx.x;
    int t = tid >> 13, e = tid & (EE - 1);
    int d = dst[tid];
    int row = t * NN + d;
    int pos = atomicAdd(&cnt[row], 1);
    if (pos < CAP) esw[(size_t)row * 2 * CAP + 2 * pos] = e;
  } else if (bid < 2048 + 47){                        // ---- weight prep
    int tid = (bid - 2048) * 256 + threadIdx.x;
    if (tid < 2048){
      int lane = tid & 63, kc = (tid >> 6) & 3, ct = tid >> 8;
      int g = lane >> 4, l15 = lane & 15;
      #pragma unroll
      for (int j = 0; j < 8; ++j){
        int k = kc * 32 + g * 8 + j;
        int col = ct * 16 + l15;
        float v = Wp[k * DD + col];
        uint16_t h = f2bf(v);
        WpHi[(size_t)tid * 8 + j] = h;
        WpLo[(size_t)tid * 8 + j] = f2bf(v - bf2f(h));
      }
    } else if (tid < 2048 + 9216){
      int idx = tid - 2048;
      int lane = idx & 63, kc = (idx >> 6) & 3, t2 = idx >> 8;  // t2 = m*12+h
      int h = t2 % 12, m = t2 / 12;
      const float* W = (m == 0) ? Wq : (m == 1) ? Wk : Wv;
      int g = lane >> 4, l15 = lane & 15;
      #pragma unroll
      for (int j = 0; j < 8; ++j){
        int k = kc * 32 + g * 8 + j;
        float v = (l15 < 10) ? W[k * 120 + h * 10 + l15] : 0.f;
        QHi[(size_t)idx * 8 + j] = f2bf(v);
      }
    } else if (tid < 2048 + 9216 + 576){
      int idx = tid - (2048 + 9216);
      int m = idx / 192, rest = idx % 192;
      int h = rest / 16, d = rest % 16;
      const float* B = (m == 0) ? bq : (m == 1) ? bk : bv;
      biasPad[idx] = (d < 10) ? B[h * 10 + d] : 0.f;
    }
  } else {                                            // ---- x0 = emb[ids] (T*N*16 threads)
    int tid = (bid - 2095) * 256 + threadIdx.x;
    int row = tid >> 4, c8 = tid & 15;
    int id = ids[row];
    const float* er = emb + (size_t)id * DD + c8 * 8;
    float4 a = *(const float4*)er;
    float4 b = *(const float4*)(er + 4);
    union { uint32_t u[4]; bvec8 v; } o;
    o.u[0] = cvtpk(a.x, a.y);
    o.u[1] = cvtpk(a.z, a.w);
    o.u[2] = cvtpk(b.x, b.y);
    o.u[3] = cvtpk(b.z, b.w);
    *(bvec8*)(x + (size_t)row * DD + c8 * 8) = o.v;
  }
}

// in-place: sort edge ids (stride-2 keys, deterministic), then convert to (src, weight)
__global__ void k_sortconv(int* __restrict__ cnt, int* __restrict__ esw,
                           const int* __restrict__ srcA, const float* __restrict__ ewA){
  int row = blockIdx.x * 256 + threadIdx.x;          // T*N threads
  if (row >= TT * NN) return;
  int t = row >> 11;
  int c = cnt[row]; if (c > CAP) c = CAP;
  cnt[row] = c;
  int* p = esw + (size_t)row * 2 * CAP;
  for (int i = 0; i < c; ++i){                        // selection sort ascending
    int mi = i, mv = p[2 * i];
    for (int j = i + 1; j < c; ++j){ int vj = p[2 * j]; if (vj < mv){ mv = vj; mi = j; } }
    if (mi != i){ p[2 * mi] = p[2 * i]; p[2 * i] = mv; }
  }
  const int* srcT = srcA + (size_t)t * EE;
  const float* ewT = ewA + (size_t)t * EE;
  for (int i = 0; i < c; ++i){
    int e = p[2 * i];
    p[2 * i]     = srcT[e];
    p[2 * i + 1] = __float_as_int(ewT[e]);
  }
}

// ---------------- fused propagate: n_hat = x + scatter; out = n_hat@Wp + bp ----------------
// 16-row blocks (grid 8192): each wave gathers only 4 rows, phase 2 is
// wave-per-2-column-tiles (acc[2]). CSR heads staged in LDS; 6 blocks/CU.
// r11-proven config; r12/r13 alternatives both worse.
__global__ __launch_bounds__(256, 6) void k_prop(const uint16_t* __restrict__ xin,
    uint16_t* __restrict__ xout, const int* __restrict__ cnt, const int* __restrict__ esw,
    const uint16_t* __restrict__ WHi, const uint16_t* __restrict__ WLo,
    const float* __restrict__ bp, int topt){
  __shared__ uint16_t lds[16 * 136];                  // 4352 B
  __shared__ int4 eplds[64];                          // 16 rows x first 8 (src,w) pairs
  int vb = blockIdx.x;
  int b = ((vb & 7) << 10) | (vb >> 3);               // XCD swizzle: 8 t-slices per XCD
  int t = b >> 7, n0 = (b & 127) << 4;
  int tid = threadIdx.x, w = tid >> 6, lane = tid & 63, g = lane >> 4, l15 = lane & 15;
  const uint16_t* xt = xin + (size_t)t * NN * DD;
  int baseRow = t * NN + n0;
  if (tid < 64)
    eplds[tid] = ((const int4*)(esw + (size_t)(baseRow + (tid >> 2)) * 2 * CAP))[tid & 3];
  int myc = (lane < 16) ? cnt[baseRow + lane] : 0;
  __syncthreads();
  // phase 1: 4 rows per wave, flat-8 predicated gather
  #pragma unroll 2
  for (int i = 0; i < 4; ++i){
    int r = w * 4 + i;
    int n = n0 + r;
    uint32_t u = *(const uint32_t*)(xt + (size_t)n * DD + (lane << 1));
    int c = __shfl(myc, r);                           // wave-uniform
    const int4* epr = &eplds[r * 4];                  // LDS broadcast reads
    int4 q0 = epr[0], q1 = epr[1], q2 = epr[2], q3 = epr[3];
    int sj[8]   = {q0.x, q0.z, q1.x, q1.z, q2.x, q2.z, q3.x, q3.z};
    float wj[8] = {__int_as_float(q0.y), __int_as_float(q0.w),
                   __int_as_float(q1.y), __int_as_float(q1.w),
                   __int_as_float(q2.y), __int_as_float(q2.w),
                   __int_as_float(q3.y), __int_as_float(q3.w)};
    uint32_t xs[8];
    float wf[8];
    #pragma unroll
    for (int j = 0; j < 8; ++j){
      int s = (j < c) ? sj[j] : 0;                    // clamp garbage idx, zero weight
      wf[j] = (j < c) ? wj[j] : 0.f;
      xs[j] = *(const uint32_t*)(xt + (size_t)s * DD + (lane << 1));
    }
    float a0 = lo16(u);
    float a1 = hi16(u);
    #pragma unroll
    for (int j = 0; j < 8; ++j){
      a0 = fmaf(wf[j], lo16(xs[j]), a0);
      a1 = fmaf(wf[j], hi16(xs[j]), a1);
    }
    if (c > 8){                                       // rare tail (P ~ 2%)
      int rowg = baseRow + r;
      for (int j = 8; j < c; ++j){
        int s = esw[(size_t)rowg * 2 * CAP + 2 * j];
        float wt = __int_as_float(esw[(size_t)rowg * 2 * CAP + 2 * j + 1]);
        uint32_t us = *(const uint32_t*)(xt + (size_t)s * DD + (lane << 1));
        a0 = fmaf(wt, lo16(us), a0);
        a1 = fmaf(wt, hi16(us), a1);
      }
    }
    *(uint32_t*)&lds[r * 136 + (lane << 1)] = cvtpk(a0, a1);
  }
  __syncthreads();
  // phase 2: GEMM [16x128] @ [128x128]; wave w -> column tiles 2w, 2w+1
  bvec8 afr[4];
  #pragma unroll
  for (int kc = 0; kc < 4; ++kc)
    afr[kc] = *(const bvec8*)&lds[l15 * 136 + kc * 32 + g * 8];
  fvec4 acc[2];
  acc[0] = fvec4{0.f, 0.f, 0.f, 0.f};
  acc[1] = fvec4{0.f, 0.f, 0.f, 0.f};
  #pragma unroll
  for (int kc = 0; kc < 4; ++kc){
    #pragma unroll
    for (int c2 = 0; c2 < 2; ++c2){
      int ct = w * 2 + c2;
      size_t base = ((size_t)(ct * 4 + kc) * 64 + lane) * 8;
      acc[c2] = mfma16(afr[kc], *(const bvec8*)&WHi[base], acc[c2]);
      acc[c2] = mfma16(afr[kc], *(const bvec8*)&WLo[base], acc[c2]);
    }
  }
  __syncthreads();
  // epilogue: C + bias -> bf16 back into LDS
  #pragma unroll
  for (int c2 = 0; c2 < 2; ++c2){
    int col = (w * 2 + c2) * 16 + l15;
    float bias = bp[col];
    uint32_t c01 = cvtpk(acc[c2][0] + bias, acc[c2][1] + bias);
    uint32_t c23 = cvtpk(acc[c2][2] + bias, acc[c2][3] + bias);
    int r = g * 4;
    lds[(r + 0) * 136 + col] = (uint16_t)c01;
    lds[(r + 1) * 136 + col] = (uint16_t)(c01 >> 16);
    lds[(r + 2) * 136 + col] = (uint16_t)c23;
    lds[(r + 3) * 136 + col] = (uint16_t)(c23 >> 16);
  }
  __syncthreads();
  // store (topt: last round writes [n][t][d] for attention)
  {
    int r = tid >> 4, c8 = tid & 15;
    bvec8 v = *(const bvec8*)&lds[r * 136 + c8 * 8];
    size_t dstoff;
    if (topt == 0) dstoff = ((size_t)t * NN + n0 + r) * DD + c8 * 8;
    else           dstoff = (((size_t)(n0 + r)) * TT + t) * DD + c8 * 8;
    *(bvec8*)(xout + dstoff) = v;
  }
}

// ---------------- fused QKV + attention + partial mean ----------------
// Head-per-wave; register-resident attention (zero-padded K=32 trick, r7-verified).
// Q and K share A-fragments -> fused kc-loop with dual accumulators halves
// the QK LDS reads (48->32 ds_read_b128 per pass). V loop unchanged (r16).
// Normalization deferred past PV (r16-verified).
// NOTE: (256,3) is load-bearing — (256,4) squeezed VGPR 84->64 and spilled (r10).
// NOTE: in-block 3-pass loop is load-bearing — pass-per-block split NaN'd (r14).
__global__ __launch_bounds__(256, 3) void k_attn(const uint16_t* __restrict__ x3,
    const uint16_t* __restrict__ QHi, const float* __restrict__ biasPad,
    float* __restrict__ partials){
  __shared__ uint16_t seq[64 * 136];                  // 17408 B
  int n = blockIdx.x;
  int tid = threadIdx.x, w = tid >> 6, lane = tid & 63, g = lane >> 4, l15 = lane & 15;
  const uint16_t* xr = x3 + (size_t)n * TT * DD;
  #pragma unroll
  for (int p4 = 0; p4 < 4; ++p4){
    int chunk = p4 * 256 + tid, r = chunk >> 4, c8 = chunk & 15;
    *(bvec8*)&seq[r * 136 + c8 * 8] = *(const bvec8*)&xr[r * 128 + c8 * 8];
  }
  __syncthreads();                                    // the only barrier

  const float CSC = 0.31622776601683794f * 1.4426950408889634f;  // (1/sqrt(10))*log2(e)

  for (int pass = 0; pass < 3; ++pass){
    int h = pass * 4 + w;
    bvec8 qf8[4], kf8[4], vf8[4];
    // ---- Q & K fused (shared A-fragments, dual accumulators) ----
    {
      fvec4 accQ[4], accK[4];
      #pragma unroll
      for (int i = 0; i < 4; ++i){
        accQ[i] = fvec4{0.f, 0.f, 0.f, 0.f};
        accK[i] = fvec4{0.f, 0.f, 0.f, 0.f};
      }
      #pragma unroll
      for (int kc = 0; kc < 4; ++kc){
        bvec8 BQ = *(const bvec8*)&QHi[((size_t)((0 * 12 + h) * 4 + kc) * 64 + lane) * 8];
        bvec8 BK = *(const bvec8*)&QHi[((size_t)((1 * 12 + h) * 4 + kc) * 64 + lane) * 8];
        #pragma unroll
        for (int tb = 0; tb < 4; ++tb){
          bvec8 a = *(const bvec8*)&seq[(tb * 16 + l15) * 136 + kc * 32 + g * 8];
          accQ[tb] = mfma16(BQ, a, accQ[tb]);          // lane=t, regs=d
          accK[tb] = mfma16(BK, a, accK[tb]);
        }
      }
      float4 bq4 = *(const float4*)&biasPad[(0 * 12 + h) * 16 + g * 4];
      float4 bk4 = *(const float4*)&biasPad[(1 * 12 + h) * 16 + g * 4];
      #pragma unroll
      for (int tb = 0; tb < 4; ++tb){
        qf8[tb] = pack8z((accQ[tb][0] + bq4.x) * CSC, (accQ[tb][1] + bq4.y) * CSC,
                         (accQ[tb][2] + bq4.z) * CSC, (accQ[tb][3] + bq4.w) * CSC);
        kf8[tb] = pack8z(accK[tb][0] + bk4.x, accK[tb][1] + bk4.y,
                         accK[tb][2] + bk4.z, accK[tb][3] + bk4.w);
      }
    }
    // ---- V (unchanged from r16) ----
    {
      fvec4 acc[4];
      #pragma unroll
      for (int i = 0; i < 4; ++i) acc[i] = fvec4{0.f, 0.f, 0.f, 0.f};
      #pragma unroll
      for (int kc = 0; kc < 4; ++kc){
        bvec8 B = *(const bvec8*)&QHi[((size_t)((2 * 12 + h) * 4 + kc) * 64 + lane) * 8];
        #pragma unroll
        for (int tb = 0; tb < 4; ++tb){
          bvec8 a = *(const bvec8*)&seq[(tb * 16 + l15) * 136 + kc * 32 + g * 8];
          acc[tb] = mfma16(a, B, acc[tb]);             // lane=d, regs=s
        }
      }
      float bias = biasPad[(2 * 12 + h) * 16 + l15];   // per-d bias (lane=d)
      #pragma unroll
      for (int tb = 0; tb < 4; ++tb)
        vf8[tb] = pack8z(acc[tb][0] + bias, acc[tb][1] + bias,
                         acc[tb][2] + bias, acc[tb][3] + bias);
    }
    // ---- attention, all in registers ----
    float csum = 0.f;
    #pragma unroll
    for (int tb = 0; tb < 4; ++tb){
      fvec4 p[4];
      #pragma unroll
      for (int sb = 0; sb < 4; ++sb)
        p[sb] = mfma16(kf8[sb], qf8[tb], fvec4{0.f, 0.f, 0.f, 0.f});
      // exp without rowmax: scores O(0.1); softmax shift-invariant -> exact
      float s = 0.f;
      #pragma unroll
      for (int sb = 0; sb < 4; ++sb)
        #pragma unroll
        for (int rg = 0; rg < 4; ++rg){
          float pv = exp2f(p[sb][rg]);
          p[sb][rg] = pv;
          s += pv;
        }
      // PV on UNNORMALIZED P (bounded ~1.1); normalization deferred to csum.
      fvec4 o = fvec4{0.f, 0.f, 0.f, 0.f};
      #pragma unroll
      for (int sb = 0; sb < 4; ++sb){
        bvec8 pf = pack8z(p[sb][0], p[sb][1], p[sb][2], p[sb][3]);
        o = mfma16(pf, vf8[sb], o);
      }
      s += __shfl_xor(s, 16);
      s += __shfl_xor(s, 32);
      float rinv = __builtin_amdgcn_rcpf(s);
      csum += (o[0] + o[1] + o[2] + o[3]) * rinv;
    }
    csum += __shfl_xor(csum, 16);
    csum += __shfl_xor(csum, 32);
    if (g == 0 && l15 < 10)
      partials[(size_t)n * 120 + h * 10 + l15] = csum;
  }
}

// ---------------- deterministic reductions ----------------
__global__ void k_reduce(const float* __restrict__ partials, float* __restrict__ agg){
  __shared__ float red[256];
  int c = blockIdx.x, tid = threadIdx.x;
  float s = 0.f;
  for (int b = tid; b < NN; b += 256) s += partials[(size_t)b * 120 + c];
  red[tid] = s;
  __syncthreads();
  for (int st = 128; st > 0; st >>= 1){
    if (tid < st) red[tid] += red[tid + st];
    __syncthreads();
  }
  if (tid == 0) agg[c] = red[0] * (1.0f / (float)(NN * TT));
}

__global__ void k_final(const float* __restrict__ agg, const float* __restrict__ Wo,
                        const float* __restrict__ bo, float* __restrict__ out){
  __shared__ float r0[128], r1[128];
  int j = threadIdx.x;
  float a = (j < 120) ? agg[j] : 0.f;
  r0[j] = (j < 120) ? a * Wo[2 * j] : 0.f;
  r1[j] = (j < 120) ? a * Wo[2 * j + 1] : 0.f;
  __syncthreads();
  for (int st = 64; st > 0; st >>= 1){
    if (j < st){ r0[j] += r0[j + st]; r1[j] += r1[j + st]; }
    __syncthreads();
  }
  if (j == 0){ out[0] = r0[0] + bo[0]; out[1] = r1[0] + bo[1]; }
}

extern "C" void kernel_launch(void* const* d_in, const int* in_sizes, int n_in,
                              void* d_out, int out_size, void* d_ws, size_t ws_size,
                              hipStream_t stream){
  const int*   node_ids = (const int*)d_in[0];
  const int*   srcA     = (const int*)d_in[1];
  const int*   dstA     = (const int*)d_in[2];
  const float* ew       = (const float*)d_in[3];
  const float* emb      = (const float*)d_in[4];
  const float* Wp       = (const float*)d_in[5];
  const float* bp       = (const float*)d_in[6];
  const float* Wq       = (const float*)d_in[7];
  const float* bq       = (const float*)d_in[8];
  const float* Wk       = (const float*)d_in[9];
  const float* bk       = (const float*)d_in[10];
  const float* Wv       = (const float*)d_in[11];
  const float* bv       = (const float*)d_in[12];
  const float* Wo       = (const float*)d_in[13];
  const float* bo       = (const float*)d_in[14];

  char* p = (char*)d_ws;
  auto alloc = [&](size_t bytes) -> char* {
    char* r = p; p += (bytes + 255) & ~(size_t)255; return r;
  };
  // Total ~102.4 MB (proven footprint)
  uint16_t* xA    = (uint16_t*)alloc((size_t)TT * NN * DD * 2);
  uint16_t* xB    = (uint16_t*)alloc((size_t)TT * NN * DD * 2);
  int*      cnt   = (int*)alloc((size_t)TT * NN * 4);
  int*      esw   = (int*)alloc((size_t)TT * NN * 2 * CAP * 4);
  uint16_t* WpHi  = (uint16_t*)alloc(2048 * 8 * 2);
  uint16_t* WpLo  = (uint16_t*)alloc(2048 * 8 * 2);
  uint16_t* QHi   = (uint16_t*)alloc(9216 * 8 * 2);
  float*    biasP = (float*)alloc(576 * 4);
  float*    parts = (float*)alloc((size_t)NN * 120 * 4);
  float*    agg   = (float*)alloc(120 * 4);

  hipMemsetAsync(cnt, 0, (size_t)TT * NN * 4, stream);
  k_init<<<2048 + 47 + 8192, 256, 0, stream>>>(dstA, cnt, esw,
      Wp, Wq, Wk, Wv, bq, bk, bv, WpHi, WpLo, QHi, biasP,
      node_ids, emb, xA);
  k_sortconv<<<TT * NN / 256, 256, 0, stream>>>(cnt, esw, srcA, ew);
  k_prop<<<8192, 256, 0, stream>>>(xA, xB, cnt, esw, WpHi, WpLo, bp, 0);
  k_prop<<<8192, 256, 0, stream>>>(xB, xA, cnt, esw, WpHi, WpLo, bp, 0);
  k_prop<<<8192, 256, 0, stream>>>(xA, xB, cnt, esw, WpHi, WpLo, bp, 1);
  k_attn<<<NN, 256, 0, stream>>>(xB, QHi, biasP, parts);
  k_reduce<<<120, 256, 0, stream>>>(parts, agg);
  k_final<<<1, 128, 0, stream>>>(agg, Wo, bo, (float*)d_out);
}